// Round 2
// baseline (2805.813 us; speedup 1.0000x reference)
//
#include <hip/hip_runtime.h>
#include <hip/hip_bf16.h>

// ---------------------------------------------------------------------------
// VAE + supervised MoE forward, MI355X.
//   k_conv12 : conv1(1->32,relu) fused + conv2(32->64,s2,relu)  -> U: h2 [B,64,14,14]
//   k_conv3  : conv3(64->128,s2,relu), h3 written IN-PLACE into U (first 6272/12544)
//   k_fc     : h3(stride 12544) @ [w_mu|w_lv], K-split 2        -> part[4][B][64]
//   k_gate   : mu/lv, z, gating MLP, softmax, argmax            -> out, zb, idx
//   k_dfc    : z @ d_fc_w[e] + b                                -> hfc (U+0, fp32)
//   k_d1     : up2 + conv(32->64, elu)                          -> d1o (U+3211264, bf16)
//   k_d23    : [up2 + conv(64->32, elu)] fused with [conv(32->1)+sigmoid]
//              via parity-decomposed 2x2 sub-convs; d2 chunks live in LDS only.
// Peak workspace ~100.5 MB. Only the argmax expert is decoded per sample
// (identical to the reference gather). Encoder/gating strictly fp32.
// ---------------------------------------------------------------------------

#define NB 2048

static constexpr int OFF_RECON  = 0;
static constexpr int OFF_MU     = 1605632;
static constexpr int OFF_LV     = 1736704;
static constexpr int OFF_LOGITS = 1867776;
static constexpr int OFF_PROBS  = 1884160;

// workspace layout (float units)
static constexpr size_t WS_U    = 0;         // 25,690,112 fl: h2 / h3(in-place) / hfc + d1o(bf16)
static constexpr size_t WS_PART = 25690112;  // 524,288 fl
static constexpr size_t WS_Z    = 26214400;  // 131,072 fl
static constexpr size_t WS_IDX  = 26345472;  // 2,048 ints
// total 26,347,520 fl = 105,390,080 bytes
static constexpr size_t HFC_OFF = 0;         // fp32, 3,211,264 fl
static constexpr size_t D1O_OFF = 3211264;   // bf16, 25,690,112 elems (12,845,056 fl)

__device__ __forceinline__ float relu_f(float v) { return v > 0.f ? v : 0.f; }
__device__ __forceinline__ float elu_f(float v)  { return v > 0.f ? v : expm1f(v); }
__device__ __forceinline__ float blo(unsigned u) {
  unsigned v = u << 16; float f; __builtin_memcpy(&f, &v, 4); return f;
}
__device__ __forceinline__ float bhi(unsigned u) {
  unsigned v = u & 0xffff0000u; float f; __builtin_memcpy(&f, &v, 4); return f;
}

// ---------------------------------------------------------------------------
// conv1 (1->32, pad1, relu) fused with conv2 (32->64, s2, pad1, relu)
// ---------------------------------------------------------------------------
__global__ __launch_bounds__(256) void k_conv12(
    const float* __restrict__ x,
    const float* __restrict__ w1, const float* __restrict__ b1,
    const float* __restrict__ w2, const float* __restrict__ b2,
    float* __restrict__ h2)
{
  __shared__ float sX[900];
  __shared__ float sH[8 * 900];
  __shared__ float sW1[288];
  __shared__ float sW2[64 * 8 * 9];

  const int n = blockIdx.x;
  const int t = threadIdx.x;

  for (int idx = t; idx < 900; idx += 256) {
    int y = idx / 30, xx = idx % 30;
    float v = 0.f;
    if (y >= 1 && y <= 28 && xx >= 1 && xx <= 28)
      v = x[n * 784 + (y - 1) * 28 + (xx - 1)];
    sX[idx] = v;
  }
  for (int idx = t; idx < 288; idx += 256) sW1[idx] = w1[idx];
  for (int idx = t; idx < 7200; idx += 256) sH[idx] = 0.f;
  __syncthreads();

  const int cg = t >> 4;
  const int pg = t & 15;
  int off[13];
  #pragma unroll
  for (int j = 0; j < 13; ++j) {
    int p = pg * 13 + j;
    int y = p / 14, xx = p % 14;
    off[j] = (p < 196) ? ((2 * y) * 30 + 2 * xx) : 0;
  }
  float acc[4][13];
  #pragma unroll
  for (int u = 0; u < 4; ++u)
    #pragma unroll
    for (int j = 0; j < 13; ++j) acc[u][j] = 0.f;

  const int ch_i = t >> 5;
  const int lane = t & 31;

  for (int cc = 0; cc < 4; ++cc) {
    {
      const int c1 = cc * 8 + ch_i;
      float wr[9];
      #pragma unroll
      for (int k = 0; k < 9; ++k) wr[k] = sW1[c1 * 9 + k];
      const float bb = b1[c1];
      for (int k = 0; k < 25; ++k) {
        int p = lane + 32 * k;
        if (p < 784) {
          int y = p / 28, xx = p % 28;
          float v = bb;
          #pragma unroll
          for (int ky = 0; ky < 3; ++ky)
            #pragma unroll
            for (int kx = 0; kx < 3; ++kx)
              v += sX[(y + ky) * 30 + xx + kx] * wr[ky * 3 + kx];
          sH[ch_i * 900 + (y + 1) * 30 + (xx + 1)] = relu_f(v);
        }
      }
    }
    for (int idx = t; idx < 4608; idx += 256) {
      int c = idx / 72, rem = idx % 72;
      int i = rem / 9, k = rem % 9;
      sW2[idx] = w2[c * 288 + (cc * 8 + i) * 9 + k];
    }
    __syncthreads();

    #pragma unroll
    for (int i = 0; i < 8; ++i) {
      #pragma unroll
      for (int k = 0; k < 9; ++k) {
        const int ky = k / 3, kx = k % 3;
        float wr[4];
        #pragma unroll
        for (int u = 0; u < 4; ++u) wr[u] = sW2[(cg * 4 + u) * 72 + i * 9 + k];
        #pragma unroll
        for (int j = 0; j < 13; ++j) {
          float in = sH[i * 900 + off[j] + ky * 30 + kx];
          #pragma unroll
          for (int u = 0; u < 4; ++u) acc[u][j] += in * wr[u];
        }
      }
    }
    __syncthreads();
  }

  #pragma unroll
  for (int u = 0; u < 4; ++u) {
    const int c = cg * 4 + u;
    const float bb = b2[c];
    #pragma unroll
    for (int j = 0; j < 13; ++j) {
      int p = pg * 13 + j;
      if (p < 196) h2[(size_t)n * 12544 + c * 196 + p] = relu_f(acc[u][j] + bb);
    }
  }
}

// ---------------------------------------------------------------------------
// conv3 (64->128, s2, pad1, relu): reads hb[n] (h2 layout), writes h3 IN-PLACE
// into first 6272 floats of the same 12544-float slot. Safe: all global reads
// of this block finish before the final __syncthreads of the last chunk;
// writes happen after. hb intentionally NOT __restrict__.
// ---------------------------------------------------------------------------
__global__ __launch_bounds__(256) void k_conv3(
    float* hb,
    const float* __restrict__ w3, const float* __restrict__ b3)
{
  __shared__ float sIn[8 * 256];
  __shared__ float sW[128 * 8 * 9];

  const int n = blockIdx.x, t = threadIdx.x;
  const int cg = t >> 4;
  const int pg = t & 15;
  int off[4], pv[4];
  #pragma unroll
  for (int j = 0; j < 4; ++j) {
    int p = pg * 4 + j;
    pv[j] = p;
    int y = p / 7, xx = p % 7;
    off[j] = (p < 49) ? ((2 * y) * 16 + 2 * xx) : 0;
  }
  float acc[8][4];
  #pragma unroll
  for (int u = 0; u < 8; ++u)
    #pragma unroll
    for (int j = 0; j < 4; ++j) acc[u][j] = 0.f;

  for (int cc = 0; cc < 8; ++cc) {
    for (int idx = t; idx < 2048; idx += 256) {
      int i = idx >> 8, rem = idx & 255, y = rem >> 4, xx = rem & 15;
      float v = 0.f;
      if (y >= 1 && y <= 14 && xx >= 1 && xx <= 14)
        v = hb[(size_t)n * 12544 + (cc * 8 + i) * 196 + (y - 1) * 14 + (xx - 1)];
      sIn[idx] = v;
    }
    for (int idx = t; idx < 9216; idx += 256) {
      int c = idx / 72, rem = idx % 72;
      int i = rem / 9, k = rem % 9;
      sW[idx] = w3[c * 576 + (cc * 8 + i) * 9 + k];
    }
    __syncthreads();

    #pragma unroll
    for (int i = 0; i < 8; ++i) {
      #pragma unroll
      for (int k = 0; k < 9; ++k) {
        const int ky = k / 3, kx = k % 3;
        float wr[8];
        #pragma unroll
        for (int u = 0; u < 8; ++u) wr[u] = sW[(cg * 8 + u) * 72 + i * 9 + k];
        #pragma unroll
        for (int j = 0; j < 4; ++j) {
          float in = sIn[i * 256 + off[j] + ky * 16 + kx];
          #pragma unroll
          for (int u = 0; u < 8; ++u) acc[u][j] += in * wr[u];
        }
      }
    }
    __syncthreads();   // after this, ALL global reads of hb[n] are complete
  }

  #pragma unroll
  for (int u = 0; u < 8; ++u) {
    const int c = cg * 8 + u;
    const float bb = b3[c];
    #pragma unroll
    for (int j = 0; j < 4; ++j)
      if (pv[j] < 49)
        hb[(size_t)n * 12544 + c * 49 + pv[j]] = relu_f(acc[u][j] + bb);
  }
}

// ---------------------------------------------------------------------------
// fc GEMM: rows at stride 12544 (in-place h3), [2048 x 6272] @ [6272 x 64],
// mu (by=0) / lv (by=1), K-split 2 (bz). BM=64 BN=64 BK=16, 4x4/thread.
// ---------------------------------------------------------------------------
__global__ __launch_bounds__(256) void k_fc(
    const float* __restrict__ h3,
    const float* __restrict__ w_mu, const float* __restrict__ w_lv,
    float* __restrict__ part)
{
  __shared__ float As[16 * 65];
  __shared__ float Bs[16 * 64];
  const int bx = blockIdx.x, by = blockIdx.y, bz = blockIdx.z;
  const float* __restrict__ W = by ? w_lv : w_mu;
  const int t = threadIdx.x;
  const int tx = t & 15, ty = t >> 4;
  const int m0 = bx * 64;
  const int k0base = bz * 3136;
  const int ar = t >> 2, ac = (t & 3) * 4;
  const int bk = t >> 4, bn = (t & 15) * 4;
  float acc[4][4];
  #pragma unroll
  for (int i = 0; i < 4; ++i)
    #pragma unroll
    for (int j = 0; j < 4; ++j) acc[i][j] = 0.f;

  for (int kt = 0; kt < 196; ++kt) {
    const int k0 = k0base + kt * 16;
    float4 av = *(const float4*)&h3[(size_t)(m0 + ar) * 12544 + k0 + ac];
    float4 bv = *(const float4*)&W[(size_t)(k0 + bk) * 64 + bn];
    __syncthreads();
    As[(ac + 0) * 65 + ar] = av.x;
    As[(ac + 1) * 65 + ar] = av.y;
    As[(ac + 2) * 65 + ar] = av.z;
    As[(ac + 3) * 65 + ar] = av.w;
    *(float4*)&Bs[bk * 64 + bn] = bv;
    __syncthreads();
    #pragma unroll
    for (int kk = 0; kk < 16; ++kk) {
      float a[4], b[4];
      #pragma unroll
      for (int i = 0; i < 4; ++i) a[i] = As[kk * 65 + ty * 4 + i];
      #pragma unroll
      for (int j = 0; j < 4; ++j) b[j] = Bs[kk * 64 + tx * 4 + j];
      #pragma unroll
      for (int i = 0; i < 4; ++i)
        #pragma unroll
        for (int j = 0; j < 4; ++j) acc[i][j] += a[i] * b[j];
    }
  }
  const int slab = by * 2 + bz;
  #pragma unroll
  for (int i = 0; i < 4; ++i)
    #pragma unroll
    for (int j = 0; j < 4; ++j)
      part[(size_t)slab * 131072 + (size_t)(m0 + ty * 4 + i) * 64 + tx * 4 + j] = acc[i][j];
}

// ---------------------------------------------------------------------------
// gate: mu/lv assembly, z, gating MLP, softmax, argmax (strict fp32)
// ---------------------------------------------------------------------------
__global__ __launch_bounds__(64) void k_gate(
    const float* __restrict__ part,
    const float* __restrict__ b_mu, const float* __restrict__ b_lv,
    const float* __restrict__ eps,
    const float* __restrict__ gw1, const float* __restrict__ gb1,
    const float* __restrict__ gw2, const float* __restrict__ gb2,
    const float* __restrict__ gw3, const float* __restrict__ gb3,
    float* __restrict__ out, float* __restrict__ zbuf, int* __restrict__ idxbuf)
{
  __shared__ float sZ[64][65];
  __shared__ float sG1[64][65];
  __shared__ float sG2[64][33];
  const int t = threadIdx.x;
  const int m = blockIdx.x * 64 + t;

  for (int k = 0; k < 64; ++k) {
    float mu = b_mu[k] + part[(size_t)m * 64 + k] + part[131072 + (size_t)m * 64 + k];
    float lv = b_lv[k] + part[262144 + (size_t)m * 64 + k] + part[393216 + (size_t)m * 64 + k];
    out[OFF_MU + m * 64 + k] = mu;
    out[OFF_LV + m * 64 + k] = lv;
    float zz = mu + eps[m * 64 + k] * expf(0.5f * lv);
    sZ[t][k] = zz;
    zbuf[m * 64 + k] = zz;
  }
  for (int j = 0; j < 64; ++j) {
    float a = gb1[j];
    for (int k = 0; k < 64; ++k) a += sZ[t][k] * gw1[k * 64 + j];
    sG1[t][j] = relu_f(a);
  }
  for (int j = 0; j < 32; ++j) {
    float a = gb2[j];
    for (int k = 0; k < 64; ++k) a += sG1[t][k] * gw2[k * 32 + j];
    sG2[t][j] = relu_f(a);
  }
  float l[8];
  #pragma unroll
  for (int j = 0; j < 8; ++j) {
    float a = gb3[j];
    for (int k = 0; k < 32; ++k) a += sG2[t][k] * gw3[k * 8 + j];
    l[j] = a;
  }
  float mx = l[0];
  #pragma unroll
  for (int j = 1; j < 8; ++j) mx = fmaxf(mx, l[j]);
  float p[8]; float s = 0.f;
  #pragma unroll
  for (int j = 0; j < 8; ++j) { p[j] = expf(l[j] - mx); s += p[j]; }
  const float inv = 1.f / s;
  float best = -1.f; int bi = 0;
  #pragma unroll
  for (int j = 0; j < 8; ++j) {
    float pj = p[j] * inv;
    out[OFF_PROBS + m * 8 + j] = pj;
    out[OFF_LOGITS + m * 8 + j] = logf(pj + 1e-8f);
    if (pj > best) { best = pj; bi = j; }
  }
  idxbuf[m] = bi;
}

// ---------------------------------------------------------------------------
// decoder fc: z[64] @ d_fc_w[e][64][1568] + b -> hfc[1568]
// ---------------------------------------------------------------------------
__global__ __launch_bounds__(256) void k_dfc(
    const float* __restrict__ zbuf, const int* __restrict__ idxbuf,
    const float* __restrict__ fcw, const float* __restrict__ fcb,
    float* __restrict__ hfc)
{
  __shared__ float sZ[64];
  const int n = blockIdx.x, t = threadIdx.x;
  const int e = idxbuf[n];
  if (t < 64) sZ[t] = zbuf[n * 64 + t];
  __syncthreads();
  const float* __restrict__ W = fcw + (size_t)e * 100352;
  for (int j = t; j < 1568; j += 256) {
    float acc = fcb[e * 1568 + j];
    #pragma unroll 8
    for (int k = 0; k < 64; ++k) acc += sZ[k] * W[k * 1568 + j];
    hfc[(size_t)n * 1568 + j] = acc;
  }
}

// ---------------------------------------------------------------------------
// decoder conv1: up2(7->14) + conv(32->64, pad1) + elu -> bf16 d1o
// ---------------------------------------------------------------------------
__global__ __launch_bounds__(256) void k_d1(
    const float* __restrict__ hfc, const int* __restrict__ idxbuf,
    const float* __restrict__ w, const float* __restrict__ b,
    __hip_bfloat16* __restrict__ d1o)
{
  __shared__ float sIn[32 * 256];
  __shared__ float sW[64 * 8 * 9];
  const int n = blockIdx.x, t = threadIdx.x;
  const int e = idxbuf[n];

  for (int idx = t; idx < 8192; idx += 256) {
    int ic = idx >> 8, rem = idx & 255, y = rem >> 4, xx = rem & 15;
    float v = 0.f;
    if (y >= 1 && y <= 14 && xx >= 1 && xx <= 14)
      v = hfc[(size_t)n * 1568 + ic * 49 + ((y - 1) >> 1) * 7 + ((xx - 1) >> 1)];
    sIn[idx] = v;
  }

  const int cg = t >> 4, pg = t & 15;
  int off[13];
  #pragma unroll
  for (int j = 0; j < 13; ++j) {
    int p = pg * 13 + j;
    int y = p / 14, xx = p % 14;
    off[j] = (p < 196) ? (y * 16 + xx) : 0;
  }
  float acc[4][13];
  #pragma unroll
  for (int u = 0; u < 4; ++u)
    #pragma unroll
    for (int j = 0; j < 13; ++j) acc[u][j] = 0.f;

  for (int cc = 0; cc < 4; ++cc) {
    for (int idx = t; idx < 4608; idx += 256) {
      int c = idx / 72, rem = idx % 72;
      int i = rem / 9, k = rem % 9;
      sW[idx] = w[(size_t)e * 18432 + c * 288 + (cc * 8 + i) * 9 + k];
    }
    __syncthreads();
    #pragma unroll
    for (int i = 0; i < 8; ++i) {
      #pragma unroll
      for (int k = 0; k < 9; ++k) {
        const int ky = k / 3, kx = k % 3;
        float wr[4];
        #pragma unroll
        for (int u = 0; u < 4; ++u) wr[u] = sW[(cg * 4 + u) * 72 + i * 9 + k];
        #pragma unroll
        for (int j = 0; j < 13; ++j) {
          float in = sIn[(cc * 8 + i) * 256 + off[j] + ky * 16 + kx];
          #pragma unroll
          for (int u = 0; u < 4; ++u) acc[u][j] += in * wr[u];
        }
      }
    }
    __syncthreads();
  }

  #pragma unroll
  for (int u = 0; u < 4; ++u) {
    const int c = cg * 4 + u;
    const float bb = b[e * 64 + c];
    #pragma unroll
    for (int j = 0; j < 13; ++j) {
      int p = pg * 13 + j;
      if (p < 196)
        d1o[(size_t)n * 12544 + c * 196 + p] = __float2bfloat16(elu_f(acc[u][j] + bb));
    }
  }
}

// ---------------------------------------------------------------------------
// fused decoder conv2 (up2 14->28 + conv 64->32 + elu) + conv3 (32->1) + sigmoid.
// up2+conv3x3 refactored into parity-dependent 2x2 sub-convs on the 14x14 d1:
//   rows, out y=2a+py: py=0 -> {row a-1: w[0][:], row a: w[1][:]+w[2][:]}
//                      py=1 -> {row a: w[0][:]+w[1][:], row a+1: w[2][:]}
//   cols, out x=2b+px: px=0 -> {col b-1: c0, col b: c1+c2}
//                      px=1 -> {col b: c0+c1, col b+1: c2}
// d2 output chunks (8 ch) live only in LDS (bf16, padded 30x30); d3 accumulates
// per-pixel in registers across chunks. One block per sample. LDS = 59,072 B.
// ---------------------------------------------------------------------------
__global__ __launch_bounds__(256) void k_d23(
    const unsigned* __restrict__ d1u,   // bf16 pairs [n][6272]
    const int* __restrict__ idxbuf,
    const float* __restrict__ w2, const float* __restrict__ b2,
    const float* __restrict__ w3, const float* __restrict__ b3,
    float* __restrict__ out)
{
  __shared__ unsigned sD1u[6272];          // 64 ch x 196 px (bf16 pairs)
  __shared__ float sW[4608];               // 8 oc x 64 ic x 9
  __shared__ __hip_bfloat16 sD2c[8 * 900]; // 8 oc, padded 30x30
  __shared__ float sW3[288];

  const int n = blockIdx.x, t = threadIdx.x;
  const int e = idxbuf[n];

  for (int j = t; j < 6272; j += 256) sD1u[j] = d1u[(size_t)n * 6272 + j];
  for (int j = t; j < 288; j += 256) sW3[j] = w3[e * 288 + j];

  const int ocL = t / 28, y = t % 28;      // valid for t < 224
  const int a = y >> 1, py = y & 1;
  const int r0 = a - 1 + py, r1 = a + py;  // r0 in [-1,13], r1 in [0,14]

  float racc[4] = {0.f, 0.f, 0.f, 0.f};

  for (int oc4 = 0; oc4 < 4; ++oc4) {
    for (int j = t; j < 4608; j += 256)
      sW[j] = w2[(size_t)e * 18432 + oc4 * 4608 + j];   // contiguous oc-chunk
    for (int j = t; j < 3600; j += 256)
      ((unsigned*)sD2c)[j] = 0u;                        // halo stays zero
    __syncthreads();

    if (t < 224) {
      float acc[28];
      #pragma unroll
      for (int q = 0; q < 28; ++q) acc[q] = 0.f;
      for (int i = 0; i < 64; ++i) {
        float w[9];
        #pragma unroll
        for (int k = 0; k < 9; ++k) w[k] = sW[(ocL * 64 + i) * 9 + k];
        float er0[3], er1[3];
        #pragma unroll
        for (int k = 0; k < 3; ++k) {
          er0[k] = py ? (w[k] + w[3 + k]) : w[k];
          er1[k] = py ? w[6 + k] : (w[3 + k] + w[6 + k]);
        }
        const float ce00 = er0[0], ce10 = er0[1] + er0[2];
        const float co00 = er0[0] + er0[1], co10 = er0[2];
        const float ce01 = er1[0], ce11 = er1[1] + er1[2];
        const float co01 = er1[0] + er1[1], co11 = er1[2];

        float f0[16], f1[16];
        f0[0] = f0[15] = f1[0] = f1[15] = 0.f;
        if (r0 >= 0) {
          const int base = i * 98 + r0 * 7;
          #pragma unroll
          for (int j2 = 0; j2 < 7; ++j2) {
            unsigned u = sD1u[base + j2];
            f0[1 + 2 * j2] = blo(u); f0[2 + 2 * j2] = bhi(u);
          }
        } else {
          #pragma unroll
          for (int q = 1; q < 15; ++q) f0[q] = 0.f;
        }
        if (r1 < 14) {
          const int base = i * 98 + r1 * 7;
          #pragma unroll
          for (int j2 = 0; j2 < 7; ++j2) {
            unsigned u = sD1u[base + j2];
            f1[1 + 2 * j2] = blo(u); f1[2 + 2 * j2] = bhi(u);
          }
        } else {
          #pragma unroll
          for (int q = 1; q < 15; ++q) f1[q] = 0.f;
        }
        #pragma unroll
        for (int bq = 0; bq < 14; ++bq) {
          acc[2 * bq]     += f0[bq] * ce00 + f0[bq + 1] * ce10
                           + f1[bq] * ce01 + f1[bq + 1] * ce11;
          acc[2 * bq + 1] += f0[bq + 1] * co00 + f0[bq + 2] * co10
                           + f1[bq + 1] * co01 + f1[bq + 2] * co11;
        }
      }
      const float bb = b2[e * 32 + oc4 * 8 + ocL];
      #pragma unroll
      for (int xq = 0; xq < 28; ++xq)
        sD2c[ocL * 900 + (y + 1) * 30 + (xq + 1)] =
            __float2bfloat16(elu_f(acc[xq] + bb));
    }
    __syncthreads();

    #pragma unroll
    for (int q = 0; q < 4; ++q) {
      int p = t + 256 * q;
      if (p < 784) {
        int yy = p / 28, xx = p % 28;
        float s = 0.f;
        for (int ic = 0; ic < 8; ++ic) {
          #pragma unroll
          for (int ky = 0; ky < 3; ++ky)
            #pragma unroll
            for (int kx = 0; kx < 3; ++kx)
              s += __bfloat162float(sD2c[ic * 900 + (yy + ky) * 30 + (xx + kx)])
                 * sW3[(oc4 * 8 + ic) * 9 + ky * 3 + kx];
        }
        racc[q] += s;
      }
    }
    __syncthreads();
  }

  const float b3e = b3[e];
  #pragma unroll
  for (int q = 0; q < 4; ++q) {
    int p = t + 256 * q;
    if (p < 784)
      out[OFF_RECON + (size_t)n * 784 + p] = 1.f / (1.f + expf(-(racc[q] + b3e)));
  }
}

// ---------------------------------------------------------------------------
extern "C" void kernel_launch(void* const* d_in, const int* in_sizes, int n_in,
                              void* d_out, int out_size, void* d_ws, size_t ws_size,
                              hipStream_t stream) {
  const float* x    = (const float*)d_in[0];
  const float* eps  = (const float*)d_in[1];
  const float* ew1  = (const float*)d_in[2];
  const float* eb1  = (const float*)d_in[3];
  const float* ew2  = (const float*)d_in[4];
  const float* eb2  = (const float*)d_in[5];
  const float* ew3  = (const float*)d_in[6];
  const float* eb3  = (const float*)d_in[7];
  const float* wmu  = (const float*)d_in[8];
  const float* bmu  = (const float*)d_in[9];
  const float* wlv  = (const float*)d_in[10];
  const float* blv  = (const float*)d_in[11];
  const float* gw1  = (const float*)d_in[12];
  const float* gb1  = (const float*)d_in[13];
  const float* gw2  = (const float*)d_in[14];
  const float* gb2  = (const float*)d_in[15];
  const float* gw3  = (const float*)d_in[16];
  const float* gb3  = (const float*)d_in[17];
  const float* dfcw = (const float*)d_in[18];
  const float* dfcb = (const float*)d_in[19];
  const float* dw1  = (const float*)d_in[20];
  const float* db1  = (const float*)d_in[21];
  const float* dw2  = (const float*)d_in[22];
  const float* db2  = (const float*)d_in[23];
  const float* dw3  = (const float*)d_in[24];
  const float* db3  = (const float*)d_in[25];

  float* out = (float*)d_out;
  float* ws  = (float*)d_ws;

  float* U    = ws + WS_U;
  float* part = ws + WS_PART;
  float* zb   = ws + WS_Z;
  int*   idx  = (int*)(ws + WS_IDX);
  float* hfc  = U + HFC_OFF;
  __hip_bfloat16* d1o = (__hip_bfloat16*)(U + D1O_OFF);

  k_conv12<<<NB, 256, 0, stream>>>(x, ew1, eb1, ew2, eb2, U);
  k_conv3 <<<NB, 256, 0, stream>>>(U, ew3, eb3);
  k_fc    <<<dim3(32, 2, 2), 256, 0, stream>>>(U, wmu, wlv, part);
  k_gate  <<<32, 64, 0, stream>>>(part, bmu, blv, eps, gw1, gb1, gw2, gb2, gw3, gb3,
                                  out, zb, idx);
  k_dfc   <<<NB, 256, 0, stream>>>(zb, idx, dfcw, dfcb, hfc);
  k_d1    <<<NB, 256, 0, stream>>>(hfc, idx, dw1, db1, d1o);
  k_d23   <<<NB, 256, 0, stream>>>((const unsigned*)d1o, idx, dw2, db2, dw3, db3, out);
}

// Round 3
// 2284.048 us; speedup vs baseline: 1.2284x; 1.2284x over previous
//
#include <hip/hip_runtime.h>
#include <hip/hip_bf16.h>

// ---------------------------------------------------------------------------
// VAE + supervised MoE forward, MI355X.
//   k_conv12 : conv1(1->32,relu) fused + conv2(32->64,s2,relu)  -> U: h2 [B,64,14,14]
//   k_conv3  : conv3(64->128,s2,relu), oc split in 2 halves (LDS 26KB),
//              h3 written IN-PLACE into U after all reads
//   k_fc     : h3(stride 12544) @ [w_mu|w_lv], K-split 2        -> part
//   k_gate   : mu/lv, z, gating MLP, softmax, argmax            -> out, zb, idx
//   k_dfc    : z @ d_fc_w[e] + b                                -> hfc (fp32)
//   k_d1     : up2 + conv(32->64) + elu  via bf16 MFMA implicit GEMM
//              C[196x64] = P[196x(9tap*32ic)] * W, K-step = one tap (32 ic)
//              output layout [n][pix196][oc64] bf16
//   k_d23    : up2 + conv(64->32)+elu fused with conv(32->1)+sigmoid.
//              d2 via parity-decomposed bf16 MFMA: 4 parities, each
//              C[196x32] = P[196x(4tap*64ic)] * Wc  (Wc = combined 2x2 taps,
//              built in LDS). d2 chunk lives only in LDS; d3 fp32 VALU.
// Decoder is bf16 (post-argmax, precision-safe); encoder/gating strict fp32.
// ---------------------------------------------------------------------------

#define NB 2048

typedef short bf16x8 __attribute__((ext_vector_type(8)));
typedef float f32x4  __attribute__((ext_vector_type(4)));

static constexpr int OFF_RECON  = 0;
static constexpr int OFF_MU     = 1605632;
static constexpr int OFF_LV     = 1736704;
static constexpr int OFF_LOGITS = 1867776;
static constexpr int OFF_PROBS  = 1884160;

// workspace layout (float units)
static constexpr size_t WS_U    = 0;         // 25,690,112 fl
static constexpr size_t WS_PART = 25690112;  // 524,288 fl
static constexpr size_t WS_Z    = 26214400;  // 131,072 fl
static constexpr size_t WS_IDX  = 26345472;  // 2,048 ints
static constexpr size_t HFC_OFF = 0;         // fp32, 3,211,264 fl
static constexpr size_t D1O_OFF = 3211264;   // bf16 [n][196][64]

__device__ __forceinline__ float relu_f(float v) { return v > 0.f ? v : 0.f; }
__device__ __forceinline__ float elu_f(float v)  { return v > 0.f ? v : expm1f(v); }
__device__ __forceinline__ short f2b(float v) {
  __hip_bfloat16 h = __float2bfloat16(v);
  short s; __builtin_memcpy(&s, &h, 2); return s;
}
__device__ __forceinline__ float blo(unsigned u) {
  unsigned v = u << 16; float f; __builtin_memcpy(&f, &v, 4); return f;
}
__device__ __forceinline__ float bhi(unsigned u) {
  unsigned v = u & 0xffff0000u; float f; __builtin_memcpy(&f, &v, 4); return f;
}

// ---------------------------------------------------------------------------
// conv1 (1->32, pad1, relu) fused with conv2 (32->64, s2, pad1, relu)
// ---------------------------------------------------------------------------
__global__ __launch_bounds__(256) void k_conv12(
    const float* __restrict__ x,
    const float* __restrict__ w1, const float* __restrict__ b1,
    const float* __restrict__ w2, const float* __restrict__ b2,
    float* __restrict__ h2)
{
  __shared__ float sX[900];
  __shared__ float sH[8 * 900];
  __shared__ float sW1[288];
  __shared__ float sW2[64 * 8 * 9];

  const int n = blockIdx.x;
  const int t = threadIdx.x;

  for (int idx = t; idx < 900; idx += 256) {
    int y = idx / 30, xx = idx % 30;
    float v = 0.f;
    if (y >= 1 && y <= 28 && xx >= 1 && xx <= 28)
      v = x[n * 784 + (y - 1) * 28 + (xx - 1)];
    sX[idx] = v;
  }
  for (int idx = t; idx < 288; idx += 256) sW1[idx] = w1[idx];
  for (int idx = t; idx < 7200; idx += 256) sH[idx] = 0.f;
  __syncthreads();

  const int cg = t >> 4;
  const int pg = t & 15;
  int off[13];
  #pragma unroll
  for (int j = 0; j < 13; ++j) {
    int p = pg * 13 + j;
    int y = p / 14, xx = p % 14;
    off[j] = (p < 196) ? ((2 * y) * 30 + 2 * xx) : 0;
  }
  float acc[4][13];
  #pragma unroll
  for (int u = 0; u < 4; ++u)
    #pragma unroll
    for (int j = 0; j < 13; ++j) acc[u][j] = 0.f;

  const int ch_i = t >> 5;
  const int lane = t & 31;

  for (int cc = 0; cc < 4; ++cc) {
    {
      const int c1 = cc * 8 + ch_i;
      float wr[9];
      #pragma unroll
      for (int k = 0; k < 9; ++k) wr[k] = sW1[c1 * 9 + k];
      const float bb = b1[c1];
      for (int k = 0; k < 25; ++k) {
        int p = lane + 32 * k;
        if (p < 784) {
          int y = p / 28, xx = p % 28;
          float v = bb;
          #pragma unroll
          for (int ky = 0; ky < 3; ++ky)
            #pragma unroll
            for (int kx = 0; kx < 3; ++kx)
              v += sX[(y + ky) * 30 + xx + kx] * wr[ky * 3 + kx];
          sH[ch_i * 900 + (y + 1) * 30 + (xx + 1)] = relu_f(v);
        }
      }
    }
    for (int idx = t; idx < 4608; idx += 256) {
      int c = idx / 72, rem = idx % 72;
      int i = rem / 9, k = rem % 9;
      sW2[idx] = w2[c * 288 + (cc * 8 + i) * 9 + k];
    }
    __syncthreads();

    #pragma unroll
    for (int i = 0; i < 8; ++i) {
      #pragma unroll
      for (int k = 0; k < 9; ++k) {
        const int ky = k / 3, kx = k % 3;
        float wr[4];
        #pragma unroll
        for (int u = 0; u < 4; ++u) wr[u] = sW2[(cg * 4 + u) * 72 + i * 9 + k];
        #pragma unroll
        for (int j = 0; j < 13; ++j) {
          float in = sH[i * 900 + off[j] + ky * 30 + kx];
          #pragma unroll
          for (int u = 0; u < 4; ++u) acc[u][j] += in * wr[u];
        }
      }
    }
    __syncthreads();
  }

  #pragma unroll
  for (int u = 0; u < 4; ++u) {
    const int c = cg * 4 + u;
    const float bb = b2[c];
    #pragma unroll
    for (int j = 0; j < 13; ++j) {
      int p = pg * 13 + j;
      if (p < 196) h2[(size_t)n * 12544 + c * 196 + p] = relu_f(acc[u][j] + bb);
    }
  }
}

// ---------------------------------------------------------------------------
// conv3 (64->128, s2, pad1, relu), oc split into 2 halves (LDS 26.6 KB for
// occupancy). Both halves accumulated in registers, in-place write at the end
// (writing earlier would corrupt h2 channels still needed by the other half).
// ---------------------------------------------------------------------------
__global__ __launch_bounds__(256) void k_conv3(
    float* hb,
    const float* __restrict__ w3, const float* __restrict__ b3)
{
  __shared__ float sIn[8 * 256];   // 8 KB
  __shared__ float sW[64 * 72];    // 18 KB  (64 oc x 8 ic x 9)

  const int n = blockIdx.x, t = threadIdx.x;
  const int cg = t >> 4;
  const int pg = t & 15;
  const int woc = t >> 2, wq = t & 3;   // weight staging: 18 contiguous each
  int off[4], pv[4];
  #pragma unroll
  for (int j = 0; j < 4; ++j) {
    int p = pg * 4 + j;
    pv[j] = p;
    int y = p / 7, xx = p % 7;
    off[j] = (p < 49) ? ((2 * y) * 16 + 2 * xx) : 0;
  }
  float acc[8][4];
  #pragma unroll
  for (int u = 0; u < 8; ++u)
    #pragma unroll
    for (int j = 0; j < 4; ++j) acc[u][j] = 0.f;

  for (int cc = 0; cc < 8; ++cc) {
    for (int idx = t; idx < 2048; idx += 256) {
      int i = idx >> 8, rem = idx & 255, y = rem >> 4, xx = rem & 15;
      float v = 0.f;
      if (y >= 1 && y <= 14 && xx >= 1 && xx <= 14)
        v = hb[(size_t)n * 12544 + (cc * 8 + i) * 196 + (y - 1) * 14 + (xx - 1)];
      sIn[idx] = v;
    }
    for (int half = 0; half < 2; ++half) {
      {
        const float* src = &w3[(size_t)(half * 64 + woc) * 576 + cc * 72 + wq * 18];
        float* dst = &sW[woc * 72 + wq * 18];
        #pragma unroll
        for (int v = 0; v < 18; ++v) dst[v] = src[v];
      }
      __syncthreads();
      #pragma unroll
      for (int i = 0; i < 8; ++i) {
        #pragma unroll
        for (int k = 0; k < 9; ++k) {
          const int ky = k / 3, kx = k % 3;
          float wr[4];
          #pragma unroll
          for (int u = 0; u < 4; ++u) wr[u] = sW[(cg * 4 + u) * 72 + i * 9 + k];
          #pragma unroll
          for (int j = 0; j < 4; ++j) {
            float in = sIn[i * 256 + off[j] + ky * 16 + kx];
            #pragma unroll
            for (int u = 0; u < 4; ++u) acc[half * 4 + u][j] += in * wr[u];
          }
        }
      }
      __syncthreads();
    }
  }

  #pragma unroll
  for (int half = 0; half < 2; ++half)
    #pragma unroll
    for (int u = 0; u < 4; ++u) {
      const int c = half * 64 + cg * 4 + u;
      const float bb = b3[c];
      #pragma unroll
      for (int j = 0; j < 4; ++j)
        if (pv[j] < 49)
          hb[(size_t)n * 12544 + c * 49 + pv[j]] = relu_f(acc[half * 4 + u][j] + bb);
    }
}

// ---------------------------------------------------------------------------
// fc GEMM: rows at stride 12544 (in-place h3), mu/lv, K-split 2
// ---------------------------------------------------------------------------
__global__ __launch_bounds__(256) void k_fc(
    const float* __restrict__ h3,
    const float* __restrict__ w_mu, const float* __restrict__ w_lv,
    float* __restrict__ part)
{
  __shared__ float As[16 * 65];
  __shared__ float Bs[16 * 64];
  const int bx = blockIdx.x, by = blockIdx.y, bz = blockIdx.z;
  const float* __restrict__ W = by ? w_lv : w_mu;
  const int t = threadIdx.x;
  const int tx = t & 15, ty = t >> 4;
  const int m0 = bx * 64;
  const int k0base = bz * 3136;
  const int ar = t >> 2, ac = (t & 3) * 4;
  const int bk = t >> 4, bn = (t & 15) * 4;
  float acc[4][4];
  #pragma unroll
  for (int i = 0; i < 4; ++i)
    #pragma unroll
    for (int j = 0; j < 4; ++j) acc[i][j] = 0.f;

  for (int kt = 0; kt < 196; ++kt) {
    const int k0 = k0base + kt * 16;
    float4 av = *(const float4*)&h3[(size_t)(m0 + ar) * 12544 + k0 + ac];
    float4 bv = *(const float4*)&W[(size_t)(k0 + bk) * 64 + bn];
    __syncthreads();
    As[(ac + 0) * 65 + ar] = av.x;
    As[(ac + 1) * 65 + ar] = av.y;
    As[(ac + 2) * 65 + ar] = av.z;
    As[(ac + 3) * 65 + ar] = av.w;
    *(float4*)&Bs[bk * 64 + bn] = bv;
    __syncthreads();
    #pragma unroll
    for (int kk = 0; kk < 16; ++kk) {
      float a[4], b[4];
      #pragma unroll
      for (int i = 0; i < 4; ++i) a[i] = As[kk * 65 + ty * 4 + i];
      #pragma unroll
      for (int j = 0; j < 4; ++j) b[j] = Bs[kk * 64 + tx * 4 + j];
      #pragma unroll
      for (int i = 0; i < 4; ++i)
        #pragma unroll
        for (int j = 0; j < 4; ++j) acc[i][j] += a[i] * b[j];
    }
  }
  const int slab = by * 2 + bz;
  #pragma unroll
  for (int i = 0; i < 4; ++i)
    #pragma unroll
    for (int j = 0; j < 4; ++j)
      part[(size_t)slab * 131072 + (size_t)(m0 + ty * 4 + i) * 64 + tx * 4 + j] = acc[i][j];
}

// ---------------------------------------------------------------------------
// gate (strict fp32)
// ---------------------------------------------------------------------------
__global__ __launch_bounds__(64) void k_gate(
    const float* __restrict__ part,
    const float* __restrict__ b_mu, const float* __restrict__ b_lv,
    const float* __restrict__ eps,
    const float* __restrict__ gw1, const float* __restrict__ gb1,
    const float* __restrict__ gw2, const float* __restrict__ gb2,
    const float* __restrict__ gw3, const float* __restrict__ gb3,
    float* __restrict__ out, float* __restrict__ zbuf, int* __restrict__ idxbuf)
{
  __shared__ float sZ[64][65];
  __shared__ float sG1[64][65];
  __shared__ float sG2[64][33];
  const int t = threadIdx.x;
  const int m = blockIdx.x * 64 + t;

  for (int k = 0; k < 64; ++k) {
    float mu = b_mu[k] + part[(size_t)m * 64 + k] + part[131072 + (size_t)m * 64 + k];
    float lv = b_lv[k] + part[262144 + (size_t)m * 64 + k] + part[393216 + (size_t)m * 64 + k];
    out[OFF_MU + m * 64 + k] = mu;
    out[OFF_LV + m * 64 + k] = lv;
    float zz = mu + eps[m * 64 + k] * expf(0.5f * lv);
    sZ[t][k] = zz;
    zbuf[m * 64 + k] = zz;
  }
  for (int j = 0; j < 64; ++j) {
    float a = gb1[j];
    for (int k = 0; k < 64; ++k) a += sZ[t][k] * gw1[k * 64 + j];
    sG1[t][j] = relu_f(a);
  }
  for (int j = 0; j < 32; ++j) {
    float a = gb2[j];
    for (int k = 0; k < 64; ++k) a += sG1[t][k] * gw2[k * 32 + j];
    sG2[t][j] = relu_f(a);
  }
  float l[8];
  #pragma unroll
  for (int j = 0; j < 8; ++j) {
    float a = gb3[j];
    for (int k = 0; k < 32; ++k) a += sG2[t][k] * gw3[k * 8 + j];
    l[j] = a;
  }
  float mx = l[0];
  #pragma unroll
  for (int j = 1; j < 8; ++j) mx = fmaxf(mx, l[j]);
  float p[8]; float s = 0.f;
  #pragma unroll
  for (int j = 0; j < 8; ++j) { p[j] = expf(l[j] - mx); s += p[j]; }
  const float inv = 1.f / s;
  float best = -1.f; int bi = 0;
  #pragma unroll
  for (int j = 0; j < 8; ++j) {
    float pj = p[j] * inv;
    out[OFF_PROBS + m * 8 + j] = pj;
    out[OFF_LOGITS + m * 8 + j] = logf(pj + 1e-8f);
    if (pj > best) { best = pj; bi = j; }
  }
  idxbuf[m] = bi;
}

// ---------------------------------------------------------------------------
// decoder fc: z[64] @ d_fc_w[e][64][1568] + b -> hfc[1568] (fp32)
// ---------------------------------------------------------------------------
__global__ __launch_bounds__(256) void k_dfc(
    const float* __restrict__ zbuf, const int* __restrict__ idxbuf,
    const float* __restrict__ fcw, const float* __restrict__ fcb,
    float* __restrict__ hfc)
{
  __shared__ float sZ[64];
  const int n = blockIdx.x, t = threadIdx.x;
  const int e = idxbuf[n];
  if (t < 64) sZ[t] = zbuf[n * 64 + t];
  __syncthreads();
  const float* __restrict__ W = fcw + (size_t)e * 100352;
  for (int j = t; j < 1568; j += 256) {
    float acc = fcb[e * 1568 + j];
    #pragma unroll 8
    for (int k = 0; k < 64; ++k) acc += sZ[k] * W[k * 1568 + j];
    hfc[(size_t)n * 1568 + j] = acc;
  }
}

// ---------------------------------------------------------------------------
// decoder conv1 via bf16 MFMA implicit GEMM.
// C[196x64] = P[196x(9*32)] * W ; K-step = one tap = 32 ic (exact MFMA K).
// LDS: up2'd+haloed input [256 pix][ic stride 40] bf16, W [tap][oc][ic] bf16.
// Wave w = n-tile (16 oc); each wave loops all 13 m-tiles.
// Output d1o[n][pix196][oc64] bf16 (pixel-major for k_d23's staging).
// ---------------------------------------------------------------------------
__global__ __launch_bounds__(256) void k_d1(
    const float* __restrict__ hfc, const int* __restrict__ idxbuf,
    const float* __restrict__ w, const float* __restrict__ b,
    __hip_bfloat16* __restrict__ d1o)
{
  __shared__ short sIn[256 * 40];   // 20,480 B
  __shared__ short sW[9 * 64 * 32]; // 36,864 B
  __shared__ float sB[64];

  const int n = blockIdx.x, t = threadIdx.x;
  const int e = idxbuf[n];

  // stage input: pixel t of the 16x16 haloed up2 image, all 32 ic
  {
    int r = t >> 4, c = t & 15;
    bool inter = (r >= 1 && r <= 14 && c >= 1 && c <= 14);
    int src = inter ? (((r - 1) >> 1) * 7 + ((c - 1) >> 1)) : 0;
    for (int ic = 0; ic < 32; ++ic) {
      float v = inter ? hfc[(size_t)n * 1568 + ic * 49 + src] : 0.f;
      sIn[t * 40 + ic] = f2b(v);
    }
  }
  // stage weights: global [64 oc][32 ic][9 tap] fp32 -> LDS [tap][oc][ic] bf16
  for (int idx = t; idx < 18432; idx += 256) {
    int tap = idx >> 11, oc = (idx >> 5) & 63, ic = idx & 31;
    sW[idx] = f2b(w[(size_t)e * 18432 + (oc * 32 + ic) * 9 + tap]);
  }
  if (t < 64) sB[t] = b[e * 64 + t];
  __syncthreads();

  const int wv = t >> 6, lane = t & 63;
  const int q = lane >> 4, m16 = lane & 15;
  const int ocl = wv * 16 + m16;

  f32x4 acc[13];
  int abase[13];
  #pragma unroll
  for (int mt = 0; mt < 13; ++mt) {
    acc[mt] = (f32x4)0.f;
    int p = mt * 16 + m16; if (p > 195) p = 195;
    int y = p / 14, x = p % 14;
    abase[mt] = (y * 16 + x) * 40 + q * 8;
  }

  for (int tap = 0; tap < 9; ++tap) {
    const int ky = tap / 3, kx = tap % 3;
    const int toff = (ky * 16 + kx) * 40;
    bf16x8 bfrag = *(const bf16x8*)&sW[tap * 2048 + ocl * 32 + q * 8];
    #pragma unroll
    for (int mt = 0; mt < 13; ++mt) {
      bf16x8 afrag = *(const bf16x8*)&sIn[abase[mt] + toff];
      acc[mt] = __builtin_amdgcn_mfma_f32_16x16x32_bf16(afrag, bfrag, acc[mt], 0, 0, 0);
    }
  }

  const float bias = sB[ocl];
  #pragma unroll
  for (int mt = 0; mt < 13; ++mt) {
    #pragma unroll
    for (int r = 0; r < 4; ++r) {
      int p = mt * 16 + q * 4 + r;
      if (p < 196) {
        float v = elu_f(acc[mt][r] + bias);
        short s = f2b(v);
        __builtin_memcpy(&d1o[(size_t)n * 12544 + p * 64 + ocl], &s, 2);
      }
    }
  }
}

// ---------------------------------------------------------------------------
// fused decoder conv2+conv3 via parity-decomposed bf16 MFMA.
// Per parity (py,px): C[196x32] = P[196x(4tap*64ic)] * Wc, 8 K-steps of 32.
// Wc (parity-combined 2x2 taps, bf16) and the d2 LDS chunk share one union
// (disjoint lifetimes). d3 accumulates per-thread in registers across
// parities; sigmoid written to d_out.
//   sU as Wc   : [s=tap*2+h][32 oc][32 ic]          (8192 shorts)
//   sU as d2buf: [p196][34] (pad 2 for bank spread)  (6664 shorts)
// ---------------------------------------------------------------------------
__global__ __launch_bounds__(256) void k_d23(
    const unsigned* __restrict__ d1u,   // bf16 pairs, [n][196 pix][32 u32]
    const int* __restrict__ idxbuf,
    const float* __restrict__ w2, const float* __restrict__ b2,
    const float* __restrict__ w3, const float* __restrict__ b3,
    float* __restrict__ out)
{
  __shared__ short sD1[256 * 72];  // 36,864 B: [pix16x16][ic64], stride 72
  __shared__ short sU[8192];       // 16,384 B union: Wc / d2buf
  __shared__ float sW3[288];       // w3[ic32][9]
  __shared__ float sB2[32];

  const int n = blockIdx.x, t = threadIdx.x;
  const int e = idxbuf[n];

  // zero sD1 (halo), then fill interior from d1o[n] (contiguous copy + remap)
  {
    unsigned* d = (unsigned*)sD1;
    for (int idx = t; idx < 9216; idx += 256) d[idx] = 0u;
  }
  __syncthreads();
  {
    unsigned* d = (unsigned*)sD1;
    for (int idx = t; idx < 6272; idx += 256) {
      unsigned v = d1u[(size_t)n * 6272 + idx];
      int p = idx >> 5, icp = idx & 31;
      int r = p / 14, c = p % 14;
      d[((r + 1) * 16 + (c + 1)) * 36 + icp] = v;
    }
  }
  for (int j = t; j < 288; j += 256) sW3[j] = w3[e * 288 + j];
  if (t < 32) sB2[t] = b2[e * 32 + t];

  const int wv = t >> 6, lane = t & 63;
  const int q = lane >> 4, m16 = lane & 15;
  const int nt = wv & 1, mh = wv >> 1;
  const int ocl = nt * 16 + m16;
  const int nm = (mh == 0) ? 7 : 6;

  // per-thread d3 output pixels
  int PY[4], PX[4];
  #pragma unroll
  for (int g = 0; g < 4; ++g) {
    int P = t + 256 * g;
    PY[g] = (P < 784) ? P / 28 : -100;
    PX[g] = (P < 784) ? P % 28 : 0;
  }
  float racc[4] = {0.f, 0.f, 0.f, 0.f};

  // m-tile A bases (parity-independent part)
  int ab0[7];
  #pragma unroll
  for (int im = 0; im < 7; ++im) {
    int mt = mh + 2 * im;
    int p = mt * 16 + m16; if (p > 195) p = 195;
    int a = p / 14, bb = p % 14;
    ab0[im] = (a * 16 + bb) * 72 + q * 8;
  }

  for (int par = 0; par < 4; ++par) {
    const int py = par >> 1, px = par & 1;

    // ---- build Wc for this parity into sU ----
    for (int v = t; v < 8192; v += 256) {
      int s = v >> 10, oc = (v >> 5) & 31, ic = v & 31;
      int tap = s >> 1, h = s & 1;
      int ty = tap >> 1, tx = tap & 1;
      int icg = h * 32 + ic;
      int ys = (ty == 0) ? 0 : (1 + py);
      int yc = (ty == py) ? 1 : 2;
      int xs = (tx == 0) ? 0 : (1 + px);
      int xc = (tx == px) ? 1 : 2;
      const float* wp = &w2[(size_t)e * 18432 + (oc * 64 + icg) * 9];
      float a = 0.f;
      for (int ky = ys; ky < ys + yc; ++ky)
        for (int kx = xs; kx < xs + xc; ++kx)
          a += wp[ky * 3 + kx];
      sU[v] = f2b(a);
    }
    __syncthreads();

    // ---- MFMA ----
    f32x4 acc[7];
    #pragma unroll
    for (int im = 0; im < 7; ++im) acc[im] = (f32x4)0.f;
    const int pbase = (py * 16 + px) * 72;
    for (int s = 0; s < 8; ++s) {
      int tap = s >> 1, h = s & 1;
      int ty = tap >> 1, tx = tap & 1;
      int toff = pbase + (ty * 16 + tx) * 72 + h * 32;
      bf16x8 bfrag = *(const bf16x8*)&sU[s * 1024 + ocl * 32 + q * 8];
      for (int im = 0; im < nm; ++im) {
        bf16x8 afrag = *(const bf16x8*)&sD1[ab0[im] + toff];
        acc[im] = __builtin_amdgcn_mfma_f32_16x16x32_bf16(afrag, bfrag, acc[im], 0, 0, 0);
      }
    }
    __syncthreads();   // all waves done reading Wc before d2buf overwrites sU

    // ---- epilogue: bias + elu -> d2buf [p196][34] bf16 ----
    {
      const float bias = sB2[ocl];
      for (int im = 0; im < nm; ++im) {
        int mt = mh + 2 * im;
        #pragma unroll
        for (int r = 0; r < 4; ++r) {
          int p = mt * 16 + q * 4 + r;
          if (p < 196) sU[p * 34 + ocl] = f2b(elu_f(acc[im][r] + bias));
        }
      }
    }
    __syncthreads();

    // ---- d3 partial accumulation for this parity ----
    #pragma unroll
    for (int g = 0; g < 4; ++g) {
      const int Y = PY[g], X = PX[g];
      if (Y < 0) continue;
      float s = 0.f;
      for (int R = Y - 1; R <= Y + 1; ++R) {
        if (R < 0 || R >= 28 || (R & 1) != py) continue;
        int ky = R - Y + 1, a = (R - py) >> 1;
        for (int C = X - 1; C <= X + 1; ++C) {
          if (C < 0 || C >= 28 || (C & 1) != px) continue;
          int kx = C - X + 1, bq = (C - px) >> 1;
          const unsigned* dp = (const unsigned*)&sU[(a * 14 + bq) * 34];
          const int wofs = ky * 3 + kx;
          #pragma unroll
          for (int i = 0; i < 16; ++i) {
            unsigned u = dp[i];
            s += blo(u) * sW3[(2 * i) * 9 + wofs] + bhi(u) * sW3[(2 * i + 1) * 9 + wofs];
          }
        }
      }
      racc[g] += s;
    }
    __syncthreads();   // d2buf consumed before next parity's Wc write
  }

  const float b3e = b3[e];
  #pragma unroll
  for (int g = 0; g < 4; ++g) {
    int P = t + 256 * g;
    if (P < 784)
      out[OFF_RECON + (size_t)n * 784 + P] = 1.f / (1.f + expf(-(racc[g] + b3e)));
  }
}

// ---------------------------------------------------------------------------
extern "C" void kernel_launch(void* const* d_in, const int* in_sizes, int n_in,
                              void* d_out, int out_size, void* d_ws, size_t ws_size,
                              hipStream_t stream) {
  const float* x    = (const float*)d_in[0];
  const float* eps  = (const float*)d_in[1];
  const float* ew1  = (const float*)d_in[2];
  const float* eb1  = (const float*)d_in[3];
  const float* ew2  = (const float*)d_in[4];
  const float* eb2  = (const float*)d_in[5];
  const float* ew3  = (const float*)d_in[6];
  const float* eb3  = (const float*)d_in[7];
  const float* wmu  = (const float*)d_in[8];
  const float* bmu  = (const float*)d_in[9];
  const float* wlv  = (const float*)d_in[10];
  const float* blv  = (const float*)d_in[11];
  const float* gw1  = (const float*)d_in[12];
  const float* gb1  = (const float*)d_in[13];
  const float* gw2  = (const float*)d_in[14];
  const float* gb2  = (const float*)d_in[15];
  const float* gw3  = (const float*)d_in[16];
  const float* gb3  = (const float*)d_in[17];
  const float* dfcw = (const float*)d_in[18];
  const float* dfcb = (const float*)d_in[19];
  const float* dw1  = (const float*)d_in[20];
  const float* db1  = (const float*)d_in[21];
  const float* dw2  = (const float*)d_in[22];
  const float* db2  = (const float*)d_in[23];
  const float* dw3  = (const float*)d_in[24];
  const float* db3  = (const float*)d_in[25];

  float* out = (float*)d_out;
  float* ws  = (float*)d_ws;

  float* U    = ws + WS_U;
  float* part = ws + WS_PART;
  float* zb   = ws + WS_Z;
  int*   idx  = (int*)(ws + WS_IDX);
  float* hfc  = U + HFC_OFF;
  __hip_bfloat16* d1o = (__hip_bfloat16*)(U + D1O_OFF);

  k_conv12<<<NB, 256, 0, stream>>>(x, ew1, eb1, ew2, eb2, U);
  k_conv3 <<<NB, 256, 0, stream>>>(U, ew3, eb3);
  k_fc    <<<dim3(32, 2, 2), 256, 0, stream>>>(U, wmu, wlv, part);
  k_gate  <<<32, 64, 0, stream>>>(part, bmu, blv, eps, gw1, gb1, gw2, gb2, gw3, gb3,
                                  out, zb, idx);
  k_dfc   <<<NB, 256, 0, stream>>>(zb, idx, dfcw, dfcb, hfc);
  k_d1    <<<NB, 256, 0, stream>>>(hfc, idx, dw1, db1, d1o);
  k_d23   <<<NB, 256, 0, stream>>>((const unsigned*)d1o, idx, dw2, db2, dw3, db3, out);
}

// Round 4
// 1969.278 us; speedup vs baseline: 1.4248x; 1.1598x over previous
//
#include <hip/hip_runtime.h>
#include <hip/hip_bf16.h>

// ---------------------------------------------------------------------------
// VAE + supervised MoE forward, MI355X.
//   k_conv12 : conv1(1->32,relu) fused + conv2(32->64,s2,relu)  -> U: h2 [B,64,14,14]
//   k_conv3  : conv3(64->128,s2,relu), oc split in 2 halves, in-place into U
//   k_fc     : h3(stride 12544) @ [w_mu|w_lv], K-split 2        -> part
//   k_gate   : mu/lv, z, gating MLP, softmax, argmax            -> out, zb, idx
//   k_prep   : one-time expert-weight repack to bf16 (into dead part region):
//              w1b[e][tap][oc64][ic32], wcb[e][par][s8][oc32][ic32]
//   k_dfc    : z @ d_fc_w[e] + b -> hfcb bf16 [n][pix49][ic32]
//   k_d1     : up2 + conv(32->64) + elu via bf16 MFMA implicit GEMM
//              (weights from w1b, contiguous loads) -> d1o [n][196][64] bf16
//   k_d23    : up2+conv(64->32)+elu fused with conv(32->1)+sigmoid; d2 via
//              parity-decomposed bf16 MFMA with precomputed Wc; d2 chunk in
//              LDS only (row stride 40 shorts = 16B aligned); d3 fp32 VALU
//              with uint4 LDS reads + tap-major w3.
// Only the argmax expert is decoded per sample. Encoder/gating strict fp32.
// ---------------------------------------------------------------------------

#define NB 2048

typedef short bf16x8 __attribute__((ext_vector_type(8)));
typedef float f32x4  __attribute__((ext_vector_type(4)));

static constexpr int OFF_RECON  = 0;
static constexpr int OFF_MU     = 1605632;
static constexpr int OFF_LV     = 1736704;
static constexpr int OFF_LOGITS = 1867776;
static constexpr int OFF_PROBS  = 1884160;

// workspace layout (float units)
static constexpr size_t WS_U    = 0;         // 25,690,112 fl
static constexpr size_t WS_PART = 25690112;  // 524,288 fl (fc partials; reused by k_prep)
static constexpr size_t WS_Z    = 26214400;  // 131,072 fl
static constexpr size_t WS_IDX  = 26345472;  // 2,048 ints
static constexpr size_t HFC_OFF = 0;         // hfcb bf16 [n][49][32] = 1,605,632 u32
static constexpr size_t D1O_OFF = 3211264;   // d1o bf16 [n][196][64]
// inside part region (after k_gate consumes it):
static constexpr size_t W1B_OFF = 0;         // 8*18432 shorts = 73,728 fl
static constexpr size_t WCB_OFF = 73728;     // 8*4*8192 shorts = 131,072 fl

__device__ __forceinline__ float relu_f(float v) { return v > 0.f ? v : 0.f; }
__device__ __forceinline__ float elu_f(float v)  { return v > 0.f ? v : expm1f(v); }
__device__ __forceinline__ short f2b(float v) {
  __hip_bfloat16 h = __float2bfloat16(v);
  short s; __builtin_memcpy(&s, &h, 2); return s;
}
__device__ __forceinline__ float blo(unsigned u) {
  unsigned v = u << 16; float f; __builtin_memcpy(&f, &v, 4); return f;
}
__device__ __forceinline__ float bhi(unsigned u) {
  unsigned v = u & 0xffff0000u; float f; __builtin_memcpy(&f, &v, 4); return f;
}

// ---------------------------------------------------------------------------
// conv1 (1->32, pad1, relu) fused with conv2 (32->64, s2, pad1, relu)
// ---------------------------------------------------------------------------
__global__ __launch_bounds__(256) void k_conv12(
    const float* __restrict__ x,
    const float* __restrict__ w1, const float* __restrict__ b1,
    const float* __restrict__ w2, const float* __restrict__ b2,
    float* __restrict__ h2)
{
  __shared__ float sX[900];
  __shared__ float sH[8 * 900];
  __shared__ float sW1[288];
  __shared__ float sW2[64 * 8 * 9];

  const int n = blockIdx.x;
  const int t = threadIdx.x;

  for (int idx = t; idx < 900; idx += 256) {
    int y = idx / 30, xx = idx % 30;
    float v = 0.f;
    if (y >= 1 && y <= 28 && xx >= 1 && xx <= 28)
      v = x[n * 784 + (y - 1) * 28 + (xx - 1)];
    sX[idx] = v;
  }
  for (int idx = t; idx < 288; idx += 256) sW1[idx] = w1[idx];
  for (int idx = t; idx < 7200; idx += 256) sH[idx] = 0.f;
  __syncthreads();

  const int cg = t >> 4;
  const int pg = t & 15;
  int off[13];
  #pragma unroll
  for (int j = 0; j < 13; ++j) {
    int p = pg * 13 + j;
    int y = p / 14, xx = p % 14;
    off[j] = (p < 196) ? ((2 * y) * 30 + 2 * xx) : 0;
  }
  float acc[4][13];
  #pragma unroll
  for (int u = 0; u < 4; ++u)
    #pragma unroll
    for (int j = 0; j < 13; ++j) acc[u][j] = 0.f;

  const int ch_i = t >> 5;
  const int lane = t & 31;

  for (int cc = 0; cc < 4; ++cc) {
    {
      const int c1 = cc * 8 + ch_i;
      float wr[9];
      #pragma unroll
      for (int k = 0; k < 9; ++k) wr[k] = sW1[c1 * 9 + k];
      const float bb = b1[c1];
      for (int k = 0; k < 25; ++k) {
        int p = lane + 32 * k;
        if (p < 784) {
          int y = p / 28, xx = p % 28;
          float v = bb;
          #pragma unroll
          for (int ky = 0; ky < 3; ++ky)
            #pragma unroll
            for (int kx = 0; kx < 3; ++kx)
              v += sX[(y + ky) * 30 + xx + kx] * wr[ky * 3 + kx];
          sH[ch_i * 900 + (y + 1) * 30 + (xx + 1)] = relu_f(v);
        }
      }
    }
    for (int idx = t; idx < 4608; idx += 256) {
      int c = idx / 72, rem = idx % 72;
      int i = rem / 9, k = rem % 9;
      sW2[idx] = w2[c * 288 + (cc * 8 + i) * 9 + k];
    }
    __syncthreads();

    #pragma unroll
    for (int i = 0; i < 8; ++i) {
      #pragma unroll
      for (int k = 0; k < 9; ++k) {
        const int ky = k / 3, kx = k % 3;
        float wr[4];
        #pragma unroll
        for (int u = 0; u < 4; ++u) wr[u] = sW2[(cg * 4 + u) * 72 + i * 9 + k];
        #pragma unroll
        for (int j = 0; j < 13; ++j) {
          float in = sH[i * 900 + off[j] + ky * 30 + kx];
          #pragma unroll
          for (int u = 0; u < 4; ++u) acc[u][j] += in * wr[u];
        }
      }
    }
    __syncthreads();
  }

  #pragma unroll
  for (int u = 0; u < 4; ++u) {
    const int c = cg * 4 + u;
    const float bb = b2[c];
    #pragma unroll
    for (int j = 0; j < 13; ++j) {
      int p = pg * 13 + j;
      if (p < 196) h2[(size_t)n * 12544 + c * 196 + p] = relu_f(acc[u][j] + bb);
    }
  }
}

// ---------------------------------------------------------------------------
// conv3 (64->128, s2, pad1, relu), oc split into 2 halves; in-place write.
// ---------------------------------------------------------------------------
__global__ __launch_bounds__(256) void k_conv3(
    float* hb,
    const float* __restrict__ w3, const float* __restrict__ b3)
{
  __shared__ float sIn[8 * 256];
  __shared__ float sW[64 * 72];

  const int n = blockIdx.x, t = threadIdx.x;
  const int cg = t >> 4;
  const int pg = t & 15;
  const int woc = t >> 2, wq = t & 3;
  int off[4], pv[4];
  #pragma unroll
  for (int j = 0; j < 4; ++j) {
    int p = pg * 4 + j;
    pv[j] = p;
    int y = p / 7, xx = p % 7;
    off[j] = (p < 49) ? ((2 * y) * 16 + 2 * xx) : 0;
  }
  float acc[8][4];
  #pragma unroll
  for (int u = 0; u < 8; ++u)
    #pragma unroll
    for (int j = 0; j < 4; ++j) acc[u][j] = 0.f;

  for (int cc = 0; cc < 8; ++cc) {
    for (int idx = t; idx < 2048; idx += 256) {
      int i = idx >> 8, rem = idx & 255, y = rem >> 4, xx = rem & 15;
      float v = 0.f;
      if (y >= 1 && y <= 14 && xx >= 1 && xx <= 14)
        v = hb[(size_t)n * 12544 + (cc * 8 + i) * 196 + (y - 1) * 14 + (xx - 1)];
      sIn[idx] = v;
    }
    for (int half = 0; half < 2; ++half) {
      {
        const float* src = &w3[(size_t)(half * 64 + woc) * 576 + cc * 72 + wq * 18];
        float* dst = &sW[woc * 72 + wq * 18];
        #pragma unroll
        for (int v = 0; v < 18; ++v) dst[v] = src[v];
      }
      __syncthreads();
      #pragma unroll
      for (int i = 0; i < 8; ++i) {
        #pragma unroll
        for (int k = 0; k < 9; ++k) {
          const int ky = k / 3, kx = k % 3;
          float wr[4];
          #pragma unroll
          for (int u = 0; u < 4; ++u) wr[u] = sW[(cg * 4 + u) * 72 + i * 9 + k];
          #pragma unroll
          for (int j = 0; j < 4; ++j) {
            float in = sIn[i * 256 + off[j] + ky * 16 + kx];
            #pragma unroll
            for (int u = 0; u < 4; ++u) acc[half * 4 + u][j] += in * wr[u];
          }
        }
      }
      __syncthreads();
    }
  }

  #pragma unroll
  for (int half = 0; half < 2; ++half)
    #pragma unroll
    for (int u = 0; u < 4; ++u) {
      const int c = half * 64 + cg * 4 + u;
      const float bb = b3[c];
      #pragma unroll
      for (int j = 0; j < 4; ++j)
        if (pv[j] < 49)
          hb[(size_t)n * 12544 + c * 49 + pv[j]] = relu_f(acc[half * 4 + u][j] + bb);
    }
}

// ---------------------------------------------------------------------------
// fc GEMM: rows at stride 12544 (in-place h3), mu/lv, K-split 2
// ---------------------------------------------------------------------------
__global__ __launch_bounds__(256) void k_fc(
    const float* __restrict__ h3,
    const float* __restrict__ w_mu, const float* __restrict__ w_lv,
    float* __restrict__ part)
{
  __shared__ float As[16 * 65];
  __shared__ float Bs[16 * 64];
  const int bx = blockIdx.x, by = blockIdx.y, bz = blockIdx.z;
  const float* __restrict__ W = by ? w_lv : w_mu;
  const int t = threadIdx.x;
  const int tx = t & 15, ty = t >> 4;
  const int m0 = bx * 64;
  const int k0base = bz * 3136;
  const int ar = t >> 2, ac = (t & 3) * 4;
  const int bk = t >> 4, bn = (t & 15) * 4;
  float acc[4][4];
  #pragma unroll
  for (int i = 0; i < 4; ++i)
    #pragma unroll
    for (int j = 0; j < 4; ++j) acc[i][j] = 0.f;

  for (int kt = 0; kt < 196; ++kt) {
    const int k0 = k0base + kt * 16;
    float4 av = *(const float4*)&h3[(size_t)(m0 + ar) * 12544 + k0 + ac];
    float4 bv = *(const float4*)&W[(size_t)(k0 + bk) * 64 + bn];
    __syncthreads();
    As[(ac + 0) * 65 + ar] = av.x;
    As[(ac + 1) * 65 + ar] = av.y;
    As[(ac + 2) * 65 + ar] = av.z;
    As[(ac + 3) * 65 + ar] = av.w;
    *(float4*)&Bs[bk * 64 + bn] = bv;
    __syncthreads();
    #pragma unroll
    for (int kk = 0; kk < 16; ++kk) {
      float a[4], b[4];
      #pragma unroll
      for (int i = 0; i < 4; ++i) a[i] = As[kk * 65 + ty * 4 + i];
      #pragma unroll
      for (int j = 0; j < 4; ++j) b[j] = Bs[kk * 64 + tx * 4 + j];
      #pragma unroll
      for (int i = 0; i < 4; ++i)
        #pragma unroll
        for (int j = 0; j < 4; ++j) acc[i][j] += a[i] * b[j];
    }
  }
  const int slab = by * 2 + bz;
  #pragma unroll
  for (int i = 0; i < 4; ++i)
    #pragma unroll
    for (int j = 0; j < 4; ++j)
      part[(size_t)slab * 131072 + (size_t)(m0 + ty * 4 + i) * 64 + tx * 4 + j] = acc[i][j];
}

// ---------------------------------------------------------------------------
// gate (strict fp32)
// ---------------------------------------------------------------------------
__global__ __launch_bounds__(64) void k_gate(
    const float* __restrict__ part,
    const float* __restrict__ b_mu, const float* __restrict__ b_lv,
    const float* __restrict__ eps,
    const float* __restrict__ gw1, const float* __restrict__ gb1,
    const float* __restrict__ gw2, const float* __restrict__ gb2,
    const float* __restrict__ gw3, const float* __restrict__ gb3,
    float* __restrict__ out, float* __restrict__ zbuf, int* __restrict__ idxbuf)
{
  __shared__ float sZ[64][65];
  __shared__ float sG1[64][65];
  __shared__ float sG2[64][33];
  const int t = threadIdx.x;
  const int m = blockIdx.x * 64 + t;

  for (int k = 0; k < 64; ++k) {
    float mu = b_mu[k] + part[(size_t)m * 64 + k] + part[131072 + (size_t)m * 64 + k];
    float lv = b_lv[k] + part[262144 + (size_t)m * 64 + k] + part[393216 + (size_t)m * 64 + k];
    out[OFF_MU + m * 64 + k] = mu;
    out[OFF_LV + m * 64 + k] = lv;
    float zz = mu + eps[m * 64 + k] * expf(0.5f * lv);
    sZ[t][k] = zz;
    zbuf[m * 64 + k] = zz;
  }
  for (int j = 0; j < 64; ++j) {
    float a = gb1[j];
    for (int k = 0; k < 64; ++k) a += sZ[t][k] * gw1[k * 64 + j];
    sG1[t][j] = relu_f(a);
  }
  for (int j = 0; j < 32; ++j) {
    float a = gb2[j];
    for (int k = 0; k < 64; ++k) a += sG1[t][k] * gw2[k * 32 + j];
    sG2[t][j] = relu_f(a);
  }
  float l[8];
  #pragma unroll
  for (int j = 0; j < 8; ++j) {
    float a = gb3[j];
    for (int k = 0; k < 32; ++k) a += sG2[t][k] * gw3[k * 8 + j];
    l[j] = a;
  }
  float mx = l[0];
  #pragma unroll
  for (int j = 1; j < 8; ++j) mx = fmaxf(mx, l[j]);
  float p[8]; float s = 0.f;
  #pragma unroll
  for (int j = 0; j < 8; ++j) { p[j] = expf(l[j] - mx); s += p[j]; }
  const float inv = 1.f / s;
  float best = -1.f; int bi = 0;
  #pragma unroll
  for (int j = 0; j < 8; ++j) {
    float pj = p[j] * inv;
    out[OFF_PROBS + m * 8 + j] = pj;
    out[OFF_LOGITS + m * 8 + j] = logf(pj + 1e-8f);
    if (pj > best) { best = pj; bi = j; }
  }
  idxbuf[m] = bi;
}

// ---------------------------------------------------------------------------
// one-time expert weight repack to bf16 (runs after k_gate, into part region).
// blockIdx.x = expert, blockIdx.y: 0 -> w1b, 1..4 -> wcb parity y-1.
// w1b[e][tap9][oc64][ic32]; wcb[e][par][s8][oc32][ic32] (s = tap2x2*2 + icHalf)
// ---------------------------------------------------------------------------
__global__ __launch_bounds__(256) void k_prep(
    const float* __restrict__ dw1, const float* __restrict__ dw2,
    unsigned short* __restrict__ w1b, unsigned short* __restrict__ wcb)
{
  const int e = blockIdx.x, job = blockIdx.y, t = threadIdx.x;
  if (job == 0) {
    for (int idx = t; idx < 18432; idx += 256) {
      int tap = idx >> 11, oc = (idx >> 5) & 63, ic = idx & 31;
      w1b[(size_t)e * 18432 + idx] =
          (unsigned short)f2b(dw1[(size_t)e * 18432 + (oc * 32 + ic) * 9 + tap]);
    }
  } else {
    const int par = job - 1, py = par >> 1, px = par & 1;
    for (int v = t; v < 8192; v += 256) {
      int s = v >> 10, oc = (v >> 5) & 31, ic = v & 31;
      int tap = s >> 1, h = s & 1;
      int ty = tap >> 1, tx = tap & 1;
      int icg = h * 32 + ic;
      int ys = (ty == 0) ? 0 : (1 + py);
      int yc = (ty == py) ? 1 : 2;
      int xs = (tx == 0) ? 0 : (1 + px);
      int xc = (tx == px) ? 1 : 2;
      const float* wp = &dw2[(size_t)e * 18432 + (oc * 64 + icg) * 9];
      float a = 0.f;
      for (int ky = ys; ky < ys + yc; ++ky)
        for (int kx = xs; kx < xs + xc; ++kx)
          a += wp[ky * 3 + kx];
      wcb[((size_t)e * 4 + par) * 8192 + v] = (unsigned short)f2b(a);
    }
  }
}

// ---------------------------------------------------------------------------
// decoder fc: z[64] @ d_fc_w[e][64][1568] + b -> hfcb bf16 [n][pix49][ic32]
// (bit-identical to old path: same f2b(acc) that k_d1 applied at staging)
// ---------------------------------------------------------------------------
__global__ __launch_bounds__(256) void k_dfc(
    const float* __restrict__ zbuf, const int* __restrict__ idxbuf,
    const float* __restrict__ fcw, const float* __restrict__ fcb,
    unsigned* __restrict__ hfcb)
{
  __shared__ float sZ[64];
  __shared__ __align__(16) unsigned short sO[1568];
  const int n = blockIdx.x, t = threadIdx.x;
  const int e = idxbuf[n];
  if (t < 64) sZ[t] = zbuf[n * 64 + t];
  __syncthreads();
  const float* __restrict__ W = fcw + (size_t)e * 100352;
  for (int j = t; j < 1568; j += 256) {
    float acc = fcb[e * 1568 + j];
    #pragma unroll 8
    for (int k = 0; k < 64; ++k) acc += sZ[k] * W[k * 1568 + j];
    int ic = j / 49, p = j % 49;           // j = ic*49 + p
    sO[p * 32 + ic] = (unsigned short)f2b(acc);
  }
  __syncthreads();
  for (int idx = t; idx < 784; idx += 256)
    hfcb[(size_t)n * 784 + idx] = ((const unsigned*)sO)[idx];
}

// ---------------------------------------------------------------------------
// decoder conv1 via bf16 MFMA implicit GEMM.
// C[196x64] = P[196x(9*32)] * W ; K-step = one tap (32 ic).
// Input from hfcb (bf16, [pix49][ic32]) -> contiguous u32 staging.
// Weights from precomputed w1b -> contiguous u32 staging.
// Output d1o[n][pix196][oc64] bf16.
// ---------------------------------------------------------------------------
__global__ __launch_bounds__(256) void k_d1(
    const unsigned* __restrict__ hfcb, const int* __restrict__ idxbuf,
    const unsigned* __restrict__ w1b, const float* __restrict__ b,
    __hip_bfloat16* __restrict__ d1o)
{
  __shared__ __align__(16) short sIn[256 * 40];   // [pix16x16 haloed][ic32 pad40]
  __shared__ __align__(16) short sW[9 * 64 * 32]; // [tap][oc][ic]
  __shared__ float sB[64];

  const int n = blockIdx.x, t = threadIdx.x;
  const int e = idxbuf[n];

  // stage input: pixel t of haloed 16x16 up2 image, 32 ic = 16 u32 contiguous
  {
    int r = t >> 4, c = t & 15;
    bool inter = (r >= 1 && r <= 14 && c >= 1 && c <= 14);
    int src = inter ? (((r - 1) >> 1) * 7 + ((c - 1) >> 1)) : 0;
    const unsigned* hp = &hfcb[(size_t)n * 784 + src * 16];
    unsigned* dst = (unsigned*)&sIn[t * 40];
    #pragma unroll
    for (int i = 0; i < 16; ++i) dst[i] = inter ? hp[i] : 0u;
  }
  // stage weights: contiguous u32 copy of precomputed bf16
  {
    const unsigned* wsrc = w1b + (size_t)e * 9216;
    unsigned* wd = (unsigned*)sW;
    for (int idx = t; idx < 9216; idx += 256) wd[idx] = wsrc[idx];
  }
  if (t < 64) sB[t] = b[e * 64 + t];
  __syncthreads();

  const int wv = t >> 6, lane = t & 63;
  const int q = lane >> 4, m16 = lane & 15;
  const int ocl = wv * 16 + m16;

  f32x4 acc[13];
  int abase[13];
  #pragma unroll
  for (int mt = 0; mt < 13; ++mt) {
    acc[mt] = (f32x4)0.f;
    int p = mt * 16 + m16; if (p > 195) p = 195;
    int y = p / 14, x = p % 14;
    abase[mt] = (y * 16 + x) * 40 + q * 8;
  }

  for (int tap = 0; tap < 9; ++tap) {
    const int ky = tap / 3, kx = tap % 3;
    const int toff = (ky * 16 + kx) * 40;
    bf16x8 bfrag = *(const bf16x8*)&sW[tap * 2048 + ocl * 32 + q * 8];
    #pragma unroll
    for (int mt = 0; mt < 13; ++mt) {
      bf16x8 afrag = *(const bf16x8*)&sIn[abase[mt] + toff];
      acc[mt] = __builtin_amdgcn_mfma_f32_16x16x32_bf16(afrag, bfrag, acc[mt], 0, 0, 0);
    }
  }

  const float bias = sB[ocl];
  #pragma unroll
  for (int mt = 0; mt < 13; ++mt) {
    #pragma unroll
    for (int r = 0; r < 4; ++r) {
      int p = mt * 16 + q * 4 + r;
      if (p < 196) {
        float v = elu_f(acc[mt][r] + bias);
        short s = f2b(v);
        __builtin_memcpy(&d1o[(size_t)n * 12544 + p * 64 + ocl], &s, 2);
      }
    }
  }
}

// ---------------------------------------------------------------------------
// fused decoder conv2+conv3 via parity-decomposed bf16 MFMA.
// Per parity: C[196x32] = P[196x(4tap*64ic)] * Wc (Wc precomputed bf16).
// sU union: Wc chunk (8192 shorts) / d2buf [p196][40] (7840 shorts, 16B rows).
// d3 accumulates per-thread fp32 across parities with uint4 LDS reads and
// tap-major w3; sigmoid to d_out.
// ---------------------------------------------------------------------------
__global__ __launch_bounds__(256) void k_d23(
    const unsigned* __restrict__ d1u,   // bf16 pairs, [n][196 pix][32 u32]
    const int* __restrict__ idxbuf,
    const unsigned* __restrict__ wcb,   // [e][par][4096 u32]
    const float* __restrict__ b2,
    const float* __restrict__ w3, const float* __restrict__ b3,
    float* __restrict__ out)
{
  __shared__ __align__(16) short sD1[256 * 72];  // [pix16x16 haloed][ic64 pad72]
  __shared__ __align__(16) short sU[8192];       // union: Wc / d2buf
  __shared__ float sW3[288];                     // tap-major: [tap9][ic32]
  __shared__ float sB2[32];

  const int n = blockIdx.x, t = threadIdx.x;
  const int e = idxbuf[n];

  {
    unsigned* d = (unsigned*)sD1;
    for (int idx = t; idx < 9216; idx += 256) d[idx] = 0u;
  }
  __syncthreads();
  {
    unsigned* d = (unsigned*)sD1;
    for (int idx = t; idx < 6272; idx += 256) {
      unsigned v = d1u[(size_t)n * 6272 + idx];
      int p = idx >> 5, icp = idx & 31;
      int r = p / 14, c = p % 14;
      d[((r + 1) * 16 + (c + 1)) * 36 + icp] = v;
    }
  }
  for (int j = t; j < 288; j += 256) {
    int tap = j >> 5, ic = j & 31;
    sW3[j] = w3[e * 288 + ic * 9 + tap];
  }
  if (t < 32) sB2[t] = b2[e * 32 + t];

  const int wv = t >> 6, lane = t & 63;
  const int q = lane >> 4, m16 = lane & 15;
  const int nt = wv & 1, mh = wv >> 1;
  const int ocl = nt * 16 + m16;
  const int nm = (mh == 0) ? 7 : 6;

  int PY[4], PX[4];
  #pragma unroll
  for (int g = 0; g < 4; ++g) {
    int P = t + 256 * g;
    PY[g] = (P < 784) ? P / 28 : -100;
    PX[g] = (P < 784) ? P % 28 : 0;
  }
  float racc[4] = {0.f, 0.f, 0.f, 0.f};

  int ab0[7];
  #pragma unroll
  for (int im = 0; im < 7; ++im) {
    int mt = mh + 2 * im;
    int p = mt * 16 + m16; if (p > 195) p = 195;
    int a = p / 14, bb = p % 14;
    ab0[im] = (a * 16 + bb) * 72 + q * 8;
  }

  for (int par = 0; par < 4; ++par) {
    const int py = par >> 1, px = par & 1;

    // ---- load precomputed Wc (coalesced) ----
    {
      const unsigned* wc = wcb + ((size_t)e * 4 + par) * 4096;
      unsigned* du = (unsigned*)sU;
      for (int v = t; v < 4096; v += 256) du[v] = wc[v];
    }
    __syncthreads();

    // ---- MFMA ----
    f32x4 acc[7];
    #pragma unroll
    for (int im = 0; im < 7; ++im) acc[im] = (f32x4)0.f;
    const int pbase = (py * 16 + px) * 72;
    for (int s = 0; s < 8; ++s) {
      int tap = s >> 1, h = s & 1;
      int ty = tap >> 1, tx = tap & 1;
      int toff = pbase + (ty * 16 + tx) * 72 + h * 32;
      bf16x8 bfrag = *(const bf16x8*)&sU[s * 1024 + ocl * 32 + q * 8];
      for (int im = 0; im < nm; ++im) {
        bf16x8 afrag = *(const bf16x8*)&sD1[ab0[im] + toff];
        acc[im] = __builtin_amdgcn_mfma_f32_16x16x32_bf16(afrag, bfrag, acc[im], 0, 0, 0);
      }
    }
    __syncthreads();   // Wc consumed before d2buf overwrites sU

    // ---- epilogue: bias + elu -> d2buf [p196][40] bf16 ----
    {
      const float bias = sB2[ocl];
      for (int im = 0; im < nm; ++im) {
        int mt = mh + 2 * im;
        #pragma unroll
        for (int r = 0; r < 4; ++r) {
          int p = mt * 16 + q * 4 + r;
          if (p < 196) sU[p * 40 + ocl] = f2b(elu_f(acc[im][r] + bias));
        }
      }
    }
    __syncthreads();

    // ---- d3 partial accumulation ----
    #pragma unroll
    for (int g = 0; g < 4; ++g) {
      const int Y = PY[g], X = PX[g];
      if (Y < 0) continue;
      float s = 0.f;
      for (int R = Y - 1; R <= Y + 1; ++R) {
        if (R < 0 || R >= 28 || (R & 1) != py) continue;
        int ky = R - Y + 1, a = (R - py) >> 1;
        for (int C = X - 1; C <= X + 1; ++C) {
          if (C < 0 || C >= 28 || (C & 1) != px) continue;
          int kx = C - X + 1, bq = (C - px) >> 1;
          const uint4* dp4 = (const uint4*)&sU[(a * 14 + bq) * 40];
          const float* wt = &sW3[(ky * 3 + kx) * 32];
          #pragma unroll
          for (int i4 = 0; i4 < 4; ++i4) {
            uint4 uu = dp4[i4];
            s += blo(uu.x) * wt[8 * i4 + 0] + bhi(uu.x) * wt[8 * i4 + 1]
               + blo(uu.y) * wt[8 * i4 + 2] + bhi(uu.y) * wt[8 * i4 + 3]
               + blo(uu.z) * wt[8 * i4 + 4] + bhi(uu.z) * wt[8 * i4 + 5]
               + blo(uu.w) * wt[8 * i4 + 6] + bhi(uu.w) * wt[8 * i4 + 7];
          }
        }
      }
      racc[g] += s;
    }
    __syncthreads();   // d2buf consumed before next parity's Wc load
  }

  const float b3e = b3[e];
  #pragma unroll
  for (int g = 0; g < 4; ++g) {
    int P = t + 256 * g;
    if (P < 784)
      out[OFF_RECON + (size_t)n * 784 + P] = 1.f / (1.f + expf(-(racc[g] + b3e)));
  }
}

// ---------------------------------------------------------------------------
extern "C" void kernel_launch(void* const* d_in, const int* in_sizes, int n_in,
                              void* d_out, int out_size, void* d_ws, size_t ws_size,
                              hipStream_t stream) {
  const float* x    = (const float*)d_in[0];
  const float* eps  = (const float*)d_in[1];
  const float* ew1  = (const float*)d_in[2];
  const float* eb1  = (const float*)d_in[3];
  const float* ew2  = (const float*)d_in[4];
  const float* eb2  = (const float*)d_in[5];
  const float* ew3  = (const float*)d_in[6];
  const float* eb3  = (const float*)d_in[7];
  const float* wmu  = (const float*)d_in[8];
  const float* bmu  = (const float*)d_in[9];
  const float* wlv  = (const float*)d_in[10];
  const float* blv  = (const float*)d_in[11];
  const float* gw1  = (const float*)d_in[12];
  const float* gb1  = (const float*)d_in[13];
  const float* gw2  = (const float*)d_in[14];
  const float* gb2  = (const float*)d_in[15];
  const float* gw3  = (const float*)d_in[16];
  const float* gb3  = (const float*)d_in[17];
  const float* dfcw = (const float*)d_in[18];
  const float* dfcb = (const float*)d_in[19];
  const float* dw1  = (const float*)d_in[20];
  const float* db1  = (const float*)d_in[21];
  const float* dw2  = (const float*)d_in[22];
  const float* db2  = (const float*)d_in[23];
  const float* dw3  = (const float*)d_in[24];
  const float* db3  = (const float*)d_in[25];

  float* out = (float*)d_out;
  float* ws  = (float*)d_ws;

  float* U    = ws + WS_U;
  float* part = ws + WS_PART;
  float* zb   = ws + WS_Z;
  int*   idx  = (int*)(ws + WS_IDX);
  unsigned* hfcb = (unsigned*)(U + HFC_OFF);
  __hip_bfloat16* d1o = (__hip_bfloat16*)(U + D1O_OFF);
  unsigned short* w1b = (unsigned short*)(part + W1B_OFF);
  unsigned short* wcb = (unsigned short*)(part + WCB_OFF);

  k_conv12<<<NB, 256, 0, stream>>>(x, ew1, eb1, ew2, eb2, U);
  k_conv3 <<<NB, 256, 0, stream>>>(U, ew3, eb3);
  k_fc    <<<dim3(32, 2, 2), 256, 0, stream>>>(U, wmu, wlv, part);
  k_gate  <<<32, 64, 0, stream>>>(part, bmu, blv, eps, gw1, gb1, gw2, gb2, gw3, gb3,
                                  out, zb, idx);
  k_prep  <<<dim3(8, 5), 256, 0, stream>>>(dw1, dw2, w1b, wcb);
  k_dfc   <<<NB, 256, 0, stream>>>(zb, idx, dfcw, dfcb, hfcb);
  k_d1    <<<NB, 256, 0, stream>>>(hfcb, idx, (const unsigned*)w1b, db1, d1o);
  k_d23   <<<NB, 256, 0, stream>>>((const unsigned*)d1o, idx, (const unsigned*)wcb,
                                   db2, dw3, db3, out);
}

// Round 5
// 1428.553 us; speedup vs baseline: 1.9641x; 1.3785x over previous
//
#include <hip/hip_runtime.h>
#include <hip/hip_bf16.h>

// ---------------------------------------------------------------------------
// VAE + supervised MoE forward, MI355X.
//   k_prep_enc: one-time 3-way bf16 split of encoder conv2/conv3 weights,
//               slot-duplicated: w2s[c4][p3][t9][oc64][k32], w3s[c8][p3][t9][oc128][k32]
//   k_conv12 : conv1 fp32 (exact) -> LDS 3-split rows; conv2 via bf16 MFMA
//              implicit GEMM, 3 passes = full (h+m+l)(wh+wm+wl) ~ fp32 precision
//              -> h2f fp32 [n][pix196][oc64]
//   k_conv3  : 4-sample blocks, ic-chunked 3-split staging + MFMA, 3 passes;
//              h3 fp32 written in-place (first 6272 fl of slot, [oc][pix])
//   k_fc     : h3(stride 12544) @ [w_mu|w_lv], K-split 2 (fp32)
//   k_gate   : mu/lv, z, gating MLP, softmax, argmax (strict fp32)
//   k_prep   : decoder weight repack to bf16 (into dead part region)
//   k_dfc    : z @ d_fc_w[e] + b -> hfcb bf16
//   k_d1     : up2+conv(32->64)+elu via bf16 MFMA -> d1o
//   k_d23    : up2+conv(64->32)+elu fused conv(32->1)+sigmoid (parity MFMA)
// Only the argmax expert is decoded per sample. Gating stays fp32-accurate.
// ---------------------------------------------------------------------------

#define NB 2048

typedef short bf16x8 __attribute__((ext_vector_type(8)));
typedef float f32x4  __attribute__((ext_vector_type(4)));

static constexpr int OFF_RECON  = 0;
static constexpr int OFF_MU     = 1605632;
static constexpr int OFF_LV     = 1736704;
static constexpr int OFF_LOGITS = 1867776;
static constexpr int OFF_PROBS  = 1884160;

// workspace layout (float units)
static constexpr size_t WS_U    = 0;         // 25,690,112 fl
static constexpr size_t WS_PART = 25690112;  // 524,288 fl (fc partials; reused by k_prep)
static constexpr size_t WS_Z    = 26214400;  // 131,072 fl
static constexpr size_t WS_IDX  = 26345472;  // 2,048 ints = 512 fl
static constexpr size_t WS_WENC = 26345984;  // encoder split weights
static constexpr size_t W2S_OFF = 0;         // 221,184 sh = 110,592 fl
static constexpr size_t W3S_OFF = 110592;    // 884,736 sh = 442,368 fl
// WS total = 26,898,944 fl ~= 107.6 MB
static constexpr size_t HFC_OFF = 0;         // hfcb bf16 [n][49][32] in U
static constexpr size_t D1O_OFF = 3211264;   // d1o bf16 [n][196][64] in U
static constexpr size_t W1B_OFF = 0;         // in part region
static constexpr size_t WCB_OFF = 73728;     // in part region

__device__ __forceinline__ float relu_f(float v) { return v > 0.f ? v : 0.f; }
__device__ __forceinline__ float elu_f(float v)  { return v > 0.f ? v : expm1f(v); }
__device__ __forceinline__ short f2b(float v) {
  __hip_bfloat16 h = __float2bfloat16(v);
  short s; __builtin_memcpy(&s, &h, 2); return s;
}
__device__ __forceinline__ float s2f(short s) {
  unsigned v = ((unsigned)(unsigned short)s) << 16;
  float f; __builtin_memcpy(&f, &v, 4); return f;
}
__device__ __forceinline__ float blo(unsigned u) {
  unsigned v = u << 16; float f; __builtin_memcpy(&f, &v, 4); return f;
}
__device__ __forceinline__ float bhi(unsigned u) {
  unsigned v = u & 0xffff0000u; float f; __builtin_memcpy(&f, &v, 4); return f;
}

// ---------------------------------------------------------------------------
// one-time encoder weight 3-split (h,m,l), slot-duplicated x4 along k.
// unit u < 55,296 -> w2s [chunk4][pass3][tap9][oc64][ic8] (each unit = 4 dup shorts)
// else            -> w3s [chunk8][pass3][tap9][oc128][ic8]
// ---------------------------------------------------------------------------
__global__ __launch_bounds__(256) void k_prep_enc(
    const float* __restrict__ ew2, const float* __restrict__ ew3,
    unsigned short* __restrict__ w2s, unsigned short* __restrict__ w3s)
{
  const int u = blockIdx.x * 256 + threadIdx.x;
  if (u >= 276480) return;
  float w; uint2* dst; int pass;
  if (u < 55296) {
    int chunk = u / 13824, r = u % 13824;
    pass = r / 4608; int r2 = r % 4608;
    int tap = r2 / 512, r3 = r2 % 512;
    int oc = r3 / 8, ic = r3 % 8;
    w = ew2[oc * 288 + (chunk * 8 + ic) * 9 + tap];
    dst = (uint2*)w2s + u;
  } else {
    int u2 = u - 55296;
    int chunk = u2 / 27648, r = u2 % 27648;
    pass = r / 9216; int r2 = r % 9216;
    int tap = r2 / 1024, r3 = r2 % 1024;
    int oc = r3 / 8, ic = r3 % 8;
    w = ew3[oc * 576 + (chunk * 8 + ic) * 9 + tap];
    dst = (uint2*)w3s + u2;
  }
  short h = f2b(w); float hf = s2f(h);
  short mm = f2b(w - hf); float mf = s2f(mm);
  short ll = f2b(w - hf - mf);
  short val = (pass == 0) ? h : (pass == 1) ? mm : ll;
  unsigned vv = (unsigned)(unsigned short)val | ((unsigned)(unsigned short)val << 16);
  uint2 pk; pk.x = vv; pk.y = vv;
  *dst = pk;
}

// ---------------------------------------------------------------------------
// conv1 (1->32, exact fp32) fused with conv2 (32->64, s2) via 3-split MFMA.
// sH rows: haloed 30x30 pixels, 40 shorts each (8 ic x 4 slots (h,m,l,0) + pad).
// Waves = (nth: oc-half) x (mh: mt-half). Output h2f [n][pix196][oc64] fp32.
// ---------------------------------------------------------------------------
__global__ __launch_bounds__(256, 2) void k_conv12(
    const float* __restrict__ x,
    const float* __restrict__ w1, const float* __restrict__ b1,
    const float* __restrict__ b2g, const unsigned short* __restrict__ w2s,
    float* __restrict__ h2f)
{
  __shared__ float sX[900];
  __shared__ float sB2[64];
  __shared__ __align__(16) short sH[900 * 40];

  const int n = blockIdx.x, t = threadIdx.x;

  for (int idx = t; idx < 900; idx += 256) {
    int yy = idx / 30, xx = idx % 30;
    float v = 0.f;
    if (yy >= 1 && yy <= 28 && xx >= 1 && xx <= 28)
      v = x[n * 784 + (yy - 1) * 28 + (xx - 1)];
    sX[idx] = v;
  }
  if (t < 64) sB2[t] = b2g[t];
  // zero border rows of sH once (interior overwritten each chunk)
  for (int bi = t; bi < 116; bi += 256) {
    int p;
    if (bi < 30) p = bi;
    else if (bi < 60) p = 870 + (bi - 30);
    else if (bi < 88) p = (bi - 59) * 30;
    else p = (bi - 87) * 30 + 29;
    unsigned* d = (unsigned*)&sH[p * 40];
    #pragma unroll
    for (int j = 0; j < 20; ++j) d[j] = 0u;
  }
  __syncthreads();

  // per-thread conv1 input windows (up to 4 pixels each)
  float xw[4][9];
  int hp[4]; bool pvld[4];
  #pragma unroll
  for (int i = 0; i < 4; ++i) {
    int p = t + 256 * i;
    pvld[i] = (p < 784);
    int yy = pvld[i] ? p / 28 : 0, xx = pvld[i] ? p % 28 : 0;
    hp[i] = (yy + 1) * 30 + xx + 1;
    #pragma unroll
    for (int k = 0; k < 9; ++k)
      xw[i][k] = sX[(yy + k / 3) * 30 + xx + (k % 3)];
  }

  const int lane = t & 63, wv = t >> 6;
  const int q = lane >> 4, m16 = lane & 15;
  const int nth = wv & 1, mh = wv >> 1;

  int abase[7];
  #pragma unroll
  for (int mtl = 0; mtl < 7; ++mtl) {
    int m = (mh * 7 + mtl) * 16 + m16; if (m > 195) m = 195;
    int yy = m / 14, xx = m % 14;
    abase[mtl] = (yy * 60 + xx * 2) * 40 + q * 8;
  }
  f32x4 acc[7][2];
  #pragma unroll
  for (int a = 0; a < 7; ++a) { acc[a][0] = (f32x4)0.f; acc[a][1] = (f32x4)0.f; }

  for (int c = 0; c < 4; ++c) {
    // conv1 build: ocs c*8 .. c*8+8, exact fp32 then 3-split
    #pragma unroll
    for (int o = 0; o < 8; ++o) {
      const int oc = c * 8 + o;
      float wr[9];
      #pragma unroll
      for (int k = 0; k < 9; ++k) wr[k] = w1[oc * 9 + k];
      const float bb = b1[oc];
      #pragma unroll
      for (int i = 0; i < 4; ++i) if (pvld[i]) {
        float v = bb;
        #pragma unroll
        for (int k = 0; k < 9; ++k) v += xw[i][k] * wr[k];
        v = relu_f(v);
        short h = f2b(v); float hf = s2f(h);
        short mm = f2b(v - hf); float mf = s2f(mm);
        short ll = f2b(v - hf - mf);
        uint2 pk;
        pk.x = (unsigned)(unsigned short)h | ((unsigned)(unsigned short)mm << 16);
        pk.y = (unsigned)(unsigned short)ll;
        *(uint2*)&sH[hp[i] * 40 + o * 4] = pk;
      }
    }
    __syncthreads();

    const unsigned short* wb = w2s + (size_t)c * 55296;
    for (int tap = 0; tap < 9; ++tap) {
      const int toff = ((tap / 3) * 30 + (tap % 3)) * 40;
      bf16x8 A[7];
      #pragma unroll
      for (int mtl = 0; mtl < 7; ++mtl)
        A[mtl] = *(const bf16x8*)&sH[abase[mtl] + toff];
      #pragma unroll
      for (int pass = 0; pass < 3; ++pass) {
        #pragma unroll
        for (int ntl = 0; ntl < 2; ++ntl) {
          const int ocl = nth * 32 + ntl * 16 + m16;
          bf16x8 B = *(const bf16x8*)&wb[((pass * 9 + tap) * 64 + ocl) * 32 + q * 8];
          #pragma unroll
          for (int mtl = 0; mtl < 7; ++mtl)
            acc[mtl][ntl] = __builtin_amdgcn_mfma_f32_16x16x32_bf16(A[mtl], B, acc[mtl][ntl], 0, 0, 0);
        }
      }
    }
    __syncthreads();
  }

  #pragma unroll
  for (int mtl = 0; mtl < 7; ++mtl) {
    const int mt = mh * 7 + mtl;
    #pragma unroll
    for (int ntl = 0; ntl < 2; ++ntl) {
      const int oc = nth * 32 + ntl * 16 + m16;
      const float bb = sB2[oc];
      #pragma unroll
      for (int r = 0; r < 4; ++r) {
        int p = mt * 16 + q * 4 + r;
        if (p < 196)
          h2f[(size_t)n * 12544 + p * 64 + oc] = relu_f(acc[mtl][ntl][r] + bb);
      }
    }
  }
}

// ---------------------------------------------------------------------------
// conv3 (64->128, s2) via 3-split MFMA, 4 samples per block (512 blocks).
// sIn rows: [s4][16x16 haloed pix][8ic x 4slot + pad = 40sh], restaged per
// ic-chunk with on-the-fly 3-split of fp32 h2f. B streamed from w3s (L2-hot).
// h3 fp32 written in-place [oc128][pix49] after all reads. hb NOT restrict.
// ---------------------------------------------------------------------------
__global__ __launch_bounds__(256, 2) void k_conv3(
    float* hb,
    const unsigned short* __restrict__ w3s,
    const float* __restrict__ b3)
{
  __shared__ __align__(16) short sIn[4 * 256 * 40];
  __shared__ float sB3[128];
  const int n0 = blockIdx.x * 4, t = threadIdx.x;
  if (t < 128) sB3[t] = b3[t];
  // zero border rows once (interior overwritten each chunk)
  for (int bi = t; bi < 240; bi += 256) {
    int s = bi / 60, r = bi % 60;
    int p;
    if (r < 16) p = r;
    else if (r < 32) p = 240 + (r - 16);
    else if (r < 46) p = (r - 31) * 16;
    else p = (r - 45) * 16 + 15;
    unsigned* d = (unsigned*)&sIn[(s * 256 + p) * 40];
    #pragma unroll
    for (int j = 0; j < 20; ++j) d[j] = 0u;
  }
  const int lane = t & 63, wv = t >> 6;
  const int q = lane >> 4, m16 = lane & 15;
  const int ntp = wv & 1, mh = wv >> 1;
  int abase[7];
  #pragma unroll
  for (int mtl = 0; mtl < 7; ++mtl) {
    int m = (mh * 7 + mtl) * 16 + m16; if (m > 195) m = 195;
    int s = m / 49, pix = m % 49;
    int yy = pix / 7, xx = pix % 7;
    abase[mtl] = (s * 256 + yy * 32 + xx * 2) * 40 + q * 8;
  }
  f32x4 acc[7][4];
  #pragma unroll
  for (int a = 0; a < 7; ++a)
    #pragma unroll
    for (int b = 0; b < 4; ++b) acc[a][b] = (f32x4)0.f;
  __syncthreads();

  for (int c = 0; c < 8; ++c) {
    __syncthreads();   // prior chunk's A-reads complete before overwrite
    for (int u = t; u < 784; u += 256) {
      int s = u / 196, pix = u % 196;
      int rr = pix / 14 + 1, cc = pix % 14 + 1;
      const float* src = &hb[(size_t)(n0 + s) * 12544 + pix * 64 + c * 8];
      float4 v0 = *(const float4*)src;
      float4 v1 = *(const float4*)(src + 4);
      float vv[8] = {v0.x, v0.y, v0.z, v0.w, v1.x, v1.y, v1.z, v1.w};
      short* drow = &sIn[(s * 256 + rr * 16 + cc) * 40];
      #pragma unroll
      for (int ic = 0; ic < 8; ++ic) {
        float v = vv[ic];
        short h = f2b(v); float hf = s2f(h);
        short mm = f2b(v - hf); float mf = s2f(mm);
        short ll = f2b(v - hf - mf);
        uint2 pk;
        pk.x = (unsigned)(unsigned short)h | ((unsigned)(unsigned short)mm << 16);
        pk.y = (unsigned)(unsigned short)ll;
        *(uint2*)&drow[ic * 4] = pk;
      }
    }
    __syncthreads();

    const unsigned short* wc = w3s + (size_t)c * 110592;
    for (int tap = 0; tap < 9; ++tap) {
      const int toff = ((tap / 3) * 16 + (tap % 3)) * 40;
      bf16x8 A[7];
      #pragma unroll
      for (int mtl = 0; mtl < 7; ++mtl)
        A[mtl] = *(const bf16x8*)&sIn[abase[mtl] + toff];
      #pragma unroll
      for (int pass = 0; pass < 3; ++pass) {
        #pragma unroll
        for (int ntl = 0; ntl < 4; ++ntl) {
          const int oc = ntp * 64 + ntl * 16 + m16;
          bf16x8 B = *(const bf16x8*)&wc[((pass * 9 + tap) * 128 + oc) * 32 + q * 8];
          #pragma unroll
          for (int mtl = 0; mtl < 7; ++mtl)
            acc[mtl][ntl] = __builtin_amdgcn_mfma_f32_16x16x32_bf16(A[mtl], B, acc[mtl][ntl], 0, 0, 0);
        }
      }
    }
  }

  #pragma unroll
  for (int mtl = 0; mtl < 7; ++mtl) {
    const int mt = mh * 7 + mtl;
    #pragma unroll
    for (int ntl = 0; ntl < 4; ++ntl) {
      const int oc = ntp * 64 + ntl * 16 + m16;
      const float bb = sB3[oc];
      #pragma unroll
      for (int r = 0; r < 4; ++r) {
        int m = mt * 16 + q * 4 + r;
        if (m < 196) {
          int s = m / 49, pix = m % 49;
          hb[(size_t)(n0 + s) * 12544 + oc * 49 + pix] = relu_f(acc[mtl][ntl][r] + bb);
        }
      }
    }
  }
}

// ---------------------------------------------------------------------------
// fc GEMM: rows at stride 12544 (in-place h3), mu/lv, K-split 2 (fp32)
// ---------------------------------------------------------------------------
__global__ __launch_bounds__(256) void k_fc(
    const float* __restrict__ h3,
    const float* __restrict__ w_mu, const float* __restrict__ w_lv,
    float* __restrict__ part)
{
  __shared__ float As[16 * 65];
  __shared__ float Bs[16 * 64];
  const int bx = blockIdx.x, by = blockIdx.y, bz = blockIdx.z;
  const float* __restrict__ W = by ? w_lv : w_mu;
  const int t = threadIdx.x;
  const int tx = t & 15, ty = t >> 4;
  const int m0 = bx * 64;
  const int k0base = bz * 3136;
  const int ar = t >> 2, ac = (t & 3) * 4;
  const int bk = t >> 4, bn = (t & 15) * 4;
  float acc[4][4];
  #pragma unroll
  for (int i = 0; i < 4; ++i)
    #pragma unroll
    for (int j = 0; j < 4; ++j) acc[i][j] = 0.f;

  for (int kt = 0; kt < 196; ++kt) {
    const int k0 = k0base + kt * 16;
    float4 av = *(const float4*)&h3[(size_t)(m0 + ar) * 12544 + k0 + ac];
    float4 bv = *(const float4*)&W[(size_t)(k0 + bk) * 64 + bn];
    __syncthreads();
    As[(ac + 0) * 65 + ar] = av.x;
    As[(ac + 1) * 65 + ar] = av.y;
    As[(ac + 2) * 65 + ar] = av.z;
    As[(ac + 3) * 65 + ar] = av.w;
    *(float4*)&Bs[bk * 64 + bn] = bv;
    __syncthreads();
    #pragma unroll
    for (int kk = 0; kk < 16; ++kk) {
      float a[4], b[4];
      #pragma unroll
      for (int i = 0; i < 4; ++i) a[i] = As[kk * 65 + ty * 4 + i];
      #pragma unroll
      for (int j = 0; j < 4; ++j) b[j] = Bs[kk * 64 + tx * 4 + j];
      #pragma unroll
      for (int i = 0; i < 4; ++i)
        #pragma unroll
        for (int j = 0; j < 4; ++j) acc[i][j] += a[i] * b[j];
    }
  }
  const int slab = by * 2 + bz;
  #pragma unroll
  for (int i = 0; i < 4; ++i)
    #pragma unroll
    for (int j = 0; j < 4; ++j)
      part[(size_t)slab * 131072 + (size_t)(m0 + ty * 4 + i) * 64 + tx * 4 + j] = acc[i][j];
}

// ---------------------------------------------------------------------------
// gate (strict fp32)
// ---------------------------------------------------------------------------
__global__ __launch_bounds__(64) void k_gate(
    const float* __restrict__ part,
    const float* __restrict__ b_mu, const float* __restrict__ b_lv,
    const float* __restrict__ eps,
    const float* __restrict__ gw1, const float* __restrict__ gb1,
    const float* __restrict__ gw2, const float* __restrict__ gb2,
    const float* __restrict__ gw3, const float* __restrict__ gb3,
    float* __restrict__ out, float* __restrict__ zbuf, int* __restrict__ idxbuf)
{
  __shared__ float sZ[64][65];
  __shared__ float sG1[64][65];
  __shared__ float sG2[64][33];
  const int t = threadIdx.x;
  const int m = blockIdx.x * 64 + t;

  for (int k = 0; k < 64; ++k) {
    float mu = b_mu[k] + part[(size_t)m * 64 + k] + part[131072 + (size_t)m * 64 + k];
    float lv = b_lv[k] + part[262144 + (size_t)m * 64 + k] + part[393216 + (size_t)m * 64 + k];
    out[OFF_MU + m * 64 + k] = mu;
    out[OFF_LV + m * 64 + k] = lv;
    float zz = mu + eps[m * 64 + k] * expf(0.5f * lv);
    sZ[t][k] = zz;
    zbuf[m * 64 + k] = zz;
  }
  for (int j = 0; j < 64; ++j) {
    float a = gb1[j];
    for (int k = 0; k < 64; ++k) a += sZ[t][k] * gw1[k * 64 + j];
    sG1[t][j] = relu_f(a);
  }
  for (int j = 0; j < 32; ++j) {
    float a = gb2[j];
    for (int k = 0; k < 64; ++k) a += sG1[t][k] * gw2[k * 32 + j];
    sG2[t][j] = relu_f(a);
  }
  float l[8];
  #pragma unroll
  for (int j = 0; j < 8; ++j) {
    float a = gb3[j];
    for (int k = 0; k < 32; ++k) a += sG2[t][k] * gw3[k * 8 + j];
    l[j] = a;
  }
  float mx = l[0];
  #pragma unroll
  for (int j = 1; j < 8; ++j) mx = fmaxf(mx, l[j]);
  float p[8]; float s = 0.f;
  #pragma unroll
  for (int j = 0; j < 8; ++j) { p[j] = expf(l[j] - mx); s += p[j]; }
  const float inv = 1.f / s;
  float best = -1.f; int bi = 0;
  #pragma unroll
  for (int j = 0; j < 8; ++j) {
    float pj = p[j] * inv;
    out[OFF_PROBS + m * 8 + j] = pj;
    out[OFF_LOGITS + m * 8 + j] = logf(pj + 1e-8f);
    if (pj > best) { best = pj; bi = j; }
  }
  idxbuf[m] = bi;
}

// ---------------------------------------------------------------------------
// one-time decoder weight repack to bf16 (into dead part region).
// ---------------------------------------------------------------------------
__global__ __launch_bounds__(256) void k_prep(
    const float* __restrict__ dw1, const float* __restrict__ dw2,
    unsigned short* __restrict__ w1b, unsigned short* __restrict__ wcb)
{
  const int e = blockIdx.x, job = blockIdx.y, t = threadIdx.x;
  if (job == 0) {
    for (int idx = t; idx < 18432; idx += 256) {
      int tap = idx >> 11, oc = (idx >> 5) & 63, ic = idx & 31;
      w1b[(size_t)e * 18432 + idx] =
          (unsigned short)f2b(dw1[(size_t)e * 18432 + (oc * 32 + ic) * 9 + tap]);
    }
  } else {
    const int par = job - 1, py = par >> 1, px = par & 1;
    for (int v = t; v < 8192; v += 256) {
      int s = v >> 10, oc = (v >> 5) & 31, ic = v & 31;
      int tap = s >> 1, h = s & 1;
      int ty = tap >> 1, tx = tap & 1;
      int icg = h * 32 + ic;
      int ys = (ty == 0) ? 0 : (1 + py);
      int yc = (ty == py) ? 1 : 2;
      int xs = (tx == 0) ? 0 : (1 + px);
      int xc = (tx == px) ? 1 : 2;
      const float* wp = &dw2[(size_t)e * 18432 + (oc * 64 + icg) * 9];
      float a = 0.f;
      for (int ky = ys; ky < ys + yc; ++ky)
        for (int kx = xs; kx < xs + xc; ++kx)
          a += wp[ky * 3 + kx];
      wcb[((size_t)e * 4 + par) * 8192 + v] = (unsigned short)f2b(a);
    }
  }
}

// ---------------------------------------------------------------------------
// decoder fc: z[64] @ d_fc_w[e][64][1568] + b -> hfcb bf16 [n][pix49][ic32]
// ---------------------------------------------------------------------------
__global__ __launch_bounds__(256) void k_dfc(
    const float* __restrict__ zbuf, const int* __restrict__ idxbuf,
    const float* __restrict__ fcw, const float* __restrict__ fcb,
    unsigned* __restrict__ hfcb)
{
  __shared__ float sZ[64];
  __shared__ __align__(16) unsigned short sO[1568];
  const int n = blockIdx.x, t = threadIdx.x;
  const int e = idxbuf[n];
  if (t < 64) sZ[t] = zbuf[n * 64 + t];
  __syncthreads();
  const float* __restrict__ W = fcw + (size_t)e * 100352;
  for (int j = t; j < 1568; j += 256) {
    float acc = fcb[e * 1568 + j];
    #pragma unroll 8
    for (int k = 0; k < 64; ++k) acc += sZ[k] * W[k * 1568 + j];
    int ic = j / 49, p = j % 49;
    sO[p * 32 + ic] = (unsigned short)f2b(acc);
  }
  __syncthreads();
  for (int idx = t; idx < 784; idx += 256)
    hfcb[(size_t)n * 784 + idx] = ((const unsigned*)sO)[idx];
}

// ---------------------------------------------------------------------------
// decoder conv1 via bf16 MFMA implicit GEMM. Output d1o[n][196][64] bf16.
// ---------------------------------------------------------------------------
__global__ __launch_bounds__(256) void k_d1(
    const unsigned* __restrict__ hfcb, const int* __restrict__ idxbuf,
    const unsigned* __restrict__ w1b, const float* __restrict__ b,
    __hip_bfloat16* __restrict__ d1o)
{
  __shared__ __align__(16) short sIn[256 * 40];
  __shared__ __align__(16) short sW[9 * 64 * 32];
  __shared__ float sB[64];

  const int n = blockIdx.x, t = threadIdx.x;
  const int e = idxbuf[n];

  {
    int r = t >> 4, c = t & 15;
    bool inter = (r >= 1 && r <= 14 && c >= 1 && c <= 14);
    int src = inter ? (((r - 1) >> 1) * 7 + ((c - 1) >> 1)) : 0;
    const unsigned* hp = &hfcb[(size_t)n * 784 + src * 16];
    unsigned* dst = (unsigned*)&sIn[t * 40];
    #pragma unroll
    for (int i = 0; i < 16; ++i) dst[i] = inter ? hp[i] : 0u;
  }
  {
    const unsigned* wsrc = w1b + (size_t)e * 9216;
    unsigned* wd = (unsigned*)sW;
    for (int idx = t; idx < 9216; idx += 256) wd[idx] = wsrc[idx];
  }
  if (t < 64) sB[t] = b[e * 64 + t];
  __syncthreads();

  const int wv = t >> 6, lane = t & 63;
  const int q = lane >> 4, m16 = lane & 15;
  const int ocl = wv * 16 + m16;

  f32x4 acc[13];
  int abase[13];
  #pragma unroll
  for (int mt = 0; mt < 13; ++mt) {
    acc[mt] = (f32x4)0.f;
    int p = mt * 16 + m16; if (p > 195) p = 195;
    int y = p / 14, x = p % 14;
    abase[mt] = (y * 16 + x) * 40 + q * 8;
  }

  for (int tap = 0; tap < 9; ++tap) {
    const int ky = tap / 3, kx = tap % 3;
    const int toff = (ky * 16 + kx) * 40;
    bf16x8 bfrag = *(const bf16x8*)&sW[tap * 2048 + ocl * 32 + q * 8];
    #pragma unroll
    for (int mt = 0; mt < 13; ++mt) {
      bf16x8 afrag = *(const bf16x8*)&sIn[abase[mt] + toff];
      acc[mt] = __builtin_amdgcn_mfma_f32_16x16x32_bf16(afrag, bfrag, acc[mt], 0, 0, 0);
    }
  }

  const float bias = sB[ocl];
  #pragma unroll
  for (int mt = 0; mt < 13; ++mt) {
    #pragma unroll
    for (int r = 0; r < 4; ++r) {
      int p = mt * 16 + q * 4 + r;
      if (p < 196) {
        float v = elu_f(acc[mt][r] + bias);
        short s = f2b(v);
        __builtin_memcpy(&d1o[(size_t)n * 12544 + p * 64 + ocl], &s, 2);
      }
    }
  }
}

// ---------------------------------------------------------------------------
// fused decoder conv2+conv3 via parity-decomposed bf16 MFMA.
// ---------------------------------------------------------------------------
__global__ __launch_bounds__(256) void k_d23(
    const unsigned* __restrict__ d1u,
    const int* __restrict__ idxbuf,
    const unsigned* __restrict__ wcb,
    const float* __restrict__ b2,
    const float* __restrict__ w3, const float* __restrict__ b3,
    float* __restrict__ out)
{
  __shared__ __align__(16) short sD1[256 * 72];
  __shared__ __align__(16) short sU[8192];
  __shared__ float sW3[288];
  __shared__ float sB2[32];

  const int n = blockIdx.x, t = threadIdx.x;
  const int e = idxbuf[n];

  {
    unsigned* d = (unsigned*)sD1;
    for (int idx = t; idx < 9216; idx += 256) d[idx] = 0u;
  }
  __syncthreads();
  {
    unsigned* d = (unsigned*)sD1;
    for (int idx = t; idx < 6272; idx += 256) {
      unsigned v = d1u[(size_t)n * 6272 + idx];
      int p = idx >> 5, icp = idx & 31;
      int r = p / 14, c = p % 14;
      d[((r + 1) * 16 + (c + 1)) * 36 + icp] = v;
    }
  }
  for (int j = t; j < 288; j += 256) {
    int tap = j >> 5, ic = j & 31;
    sW3[j] = w3[e * 288 + ic * 9 + tap];
  }
  if (t < 32) sB2[t] = b2[e * 32 + t];

  const int wv = t >> 6, lane = t & 63;
  const int q = lane >> 4, m16 = lane & 15;
  const int nt = wv & 1, mh = wv >> 1;
  const int ocl = nt * 16 + m16;
  const int nm = (mh == 0) ? 7 : 6;

  int PY[4], PX[4];
  #pragma unroll
  for (int g = 0; g < 4; ++g) {
    int P = t + 256 * g;
    PY[g] = (P < 784) ? P / 28 : -100;
    PX[g] = (P < 784) ? P % 28 : 0;
  }
  float racc[4] = {0.f, 0.f, 0.f, 0.f};

  int ab0[7];
  #pragma unroll
  for (int im = 0; im < 7; ++im) {
    int mt = mh + 2 * im;
    int p = mt * 16 + m16; if (p > 195) p = 195;
    int a = p / 14, bb = p % 14;
    ab0[im] = (a * 16 + bb) * 72 + q * 8;
  }

  for (int par = 0; par < 4; ++par) {
    const int py = par >> 1, px = par & 1;

    {
      const unsigned* wc = wcb + ((size_t)e * 4 + par) * 4096;
      unsigned* du = (unsigned*)sU;
      for (int v = t; v < 4096; v += 256) du[v] = wc[v];
    }
    __syncthreads();

    f32x4 acc[7];
    #pragma unroll
    for (int im = 0; im < 7; ++im) acc[im] = (f32x4)0.f;
    const int pbase = (py * 16 + px) * 72;
    for (int s = 0; s < 8; ++s) {
      int tap = s >> 1, h = s & 1;
      int ty = tap >> 1, tx = tap & 1;
      int toff = pbase + (ty * 16 + tx) * 72 + h * 32;
      bf16x8 bfrag = *(const bf16x8*)&sU[s * 1024 + ocl * 32 + q * 8];
      for (int im = 0; im < nm; ++im) {
        bf16x8 afrag = *(const bf16x8*)&sD1[ab0[im] + toff];
        acc[im] = __builtin_amdgcn_mfma_f32_16x16x32_bf16(afrag, bfrag, acc[im], 0, 0, 0);
      }
    }
    __syncthreads();

    {
      const float bias = sB2[ocl];
      for (int im = 0; im < nm; ++im) {
        int mt = mh + 2 * im;
        #pragma unroll
        for (int r = 0; r < 4; ++r) {
          int p = mt * 16 + q * 4 + r;
          if (p < 196) sU[p * 40 + ocl] = f2b(elu_f(acc[im][r] + bias));
        }
      }
    }
    __syncthreads();

    #pragma unroll
    for (int g = 0; g < 4; ++g) {
      const int Y = PY[g], X = PX[g];
      if (Y < 0) continue;
      float s = 0.f;
      for (int R = Y - 1; R <= Y + 1; ++R) {
        if (R < 0 || R >= 28 || (R & 1) != py) continue;
        int ky = R - Y + 1, a = (R - py) >> 1;
        for (int C = X - 1; C <= X + 1; ++C) {
          if (C < 0 || C >= 28 || (C & 1) != px) continue;
          int kx = C - X + 1, bq = (C - px) >> 1;
          const uint4* dp4 = (const uint4*)&sU[(a * 14 + bq) * 40];
          const float* wt = &sW3[(ky * 3 + kx) * 32];
          #pragma unroll
          for (int i4 = 0; i4 < 4; ++i4) {
            uint4 uu = dp4[i4];
            s += blo(uu.x) * wt[8 * i4 + 0] + bhi(uu.x) * wt[8 * i4 + 1]
               + blo(uu.y) * wt[8 * i4 + 2] + bhi(uu.y) * wt[8 * i4 + 3]
               + blo(uu.z) * wt[8 * i4 + 4] + bhi(uu.z) * wt[8 * i4 + 5]
               + blo(uu.w) * wt[8 * i4 + 6] + bhi(uu.w) * wt[8 * i4 + 7];
          }
        }
      }
      racc[g] += s;
    }
    __syncthreads();
  }

  const float b3e = b3[e];
  #pragma unroll
  for (int g = 0; g < 4; ++g) {
    int P = t + 256 * g;
    if (P < 784)
      out[OFF_RECON + (size_t)n * 784 + P] = 1.f / (1.f + expf(-(racc[g] + b3e)));
  }
}

// ---------------------------------------------------------------------------
extern "C" void kernel_launch(void* const* d_in, const int* in_sizes, int n_in,
                              void* d_out, int out_size, void* d_ws, size_t ws_size,
                              hipStream_t stream) {
  const float* x    = (const float*)d_in[0];
  const float* eps  = (const float*)d_in[1];
  const float* ew1  = (const float*)d_in[2];
  const float* eb1  = (const float*)d_in[3];
  const float* ew2  = (const float*)d_in[4];
  const float* eb2  = (const float*)d_in[5];
  const float* ew3  = (const float*)d_in[6];
  const float* eb3  = (const float*)d_in[7];
  const float* wmu  = (const float*)d_in[8];
  const float* bmu  = (const float*)d_in[9];
  const float* wlv  = (const float*)d_in[10];
  const float* blv  = (const float*)d_in[11];
  const float* gw1  = (const float*)d_in[12];
  const float* gb1  = (const float*)d_in[13];
  const float* gw2  = (const float*)d_in[14];
  const float* gb2  = (const float*)d_in[15];
  const float* gw3  = (const float*)d_in[16];
  const float* gb3  = (const float*)d_in[17];
  const float* dfcw = (const float*)d_in[18];
  const float* dfcb = (const float*)d_in[19];
  const float* dw1  = (const float*)d_in[20];
  const float* db1  = (const float*)d_in[21];
  const float* dw2  = (const float*)d_in[22];
  const float* db2  = (const float*)d_in[23];
  const float* dw3  = (const float*)d_in[24];
  const float* db3  = (const float*)d_in[25];

  float* out = (float*)d_out;
  float* ws  = (float*)d_ws;

  float* U    = ws + WS_U;
  float* part = ws + WS_PART;
  float* zb   = ws + WS_Z;
  int*   idx  = (int*)(ws + WS_IDX);
  unsigned* hfcb = (unsigned*)(U + HFC_OFF);
  __hip_bfloat16* d1o = (__hip_bfloat16*)(U + D1O_OFF);
  unsigned short* w1b = (unsigned short*)(part + W1B_OFF);
  unsigned short* wcb = (unsigned short*)(part + WCB_OFF);
  unsigned short* w2s = (unsigned short*)(ws + WS_WENC + W2S_OFF);
  unsigned short* w3s = (unsigned short*)(ws + WS_WENC + W3S_OFF);

  k_prep_enc<<<1080, 256, 0, stream>>>(ew2, ew3, w2s, w3s);
  k_conv12<<<NB, 256, 0, stream>>>(x, ew1, eb1, eb2, w2s, U);
  k_conv3 <<<512, 256, 0, stream>>>(U, w3s, eb3);
  k_fc    <<<dim3(32, 2, 2), 256, 0, stream>>>(U, wmu, wlv, part);
  k_gate  <<<32, 64, 0, stream>>>(part, bmu, blv, eps, gw1, gb1, gw2, gb2, gw3, gb3,
                                  out, zb, idx);
  k_prep  <<<dim3(8, 5), 256, 0, stream>>>(dw1, dw2, w1b, wcb);
  k_dfc   <<<NB, 256, 0, stream>>>(zb, idx, dfcw, dfcb, hfcb);
  k_d1    <<<NB, 256, 0, stream>>>(hfcb, idx, (const unsigned*)w1b, db1, d1o);
  k_d23   <<<NB, 256, 0, stream>>>((const unsigned*)d1o, idx, (const unsigned*)wcb,
                                   db2, dw3, db3, out);
}

// Round 6
// 1320.059 us; speedup vs baseline: 2.1255x; 1.0822x over previous
//
#include <hip/hip_runtime.h>
#include <hip/hip_bf16.h>

// ---------------------------------------------------------------------------
// VAE + supervised MoE forward, MI355X.
//   k_prep_enc: one-time 3-way bf16 split of encoder conv2/conv3 weights
//   k_conv12 : conv1 fp32 exact + conv2 via 3-split bf16 MFMA -> h2f fp32
//   k_conv3  : 4-sample blocks, 3-split MFMA; h3 fp32 in-place
//   k_fc     : h3(stride 12544) @ [w_mu|w_lv], K-split 2 (fp32)
//   k_gate   : mu/lv, z, gating MLP, softmax, argmax (strict fp32)
//   k_prep   : decoder weight repack to bf16 (into dead part region)
//   k_dfc    : z @ d_fc_w[e] + b -> hfcb bf16 (float4 weight stream)
//   k_d1     : up2+conv(32->64)+elu via bf16 MFMA -> d1o
//   k_d23    : up2+conv(64->32)+elu fused conv(32->1)+sigmoid.
//              d2 AND d3 both on MFMA: per parity,
//                d2: C[196x32] = P[196x(4tap*64ic)] * Wc
//                d3: C_par[196x16] = d2buf[196x32] * B3 (B3 cols0-8 = w3 taps)
//              then per-pixel gather of <=9 fp32 LDS reads total.
// Only the argmax expert is decoded per sample. Gating stays fp32-accurate.
// ---------------------------------------------------------------------------

#define NB 2048

typedef short bf16x8 __attribute__((ext_vector_type(8)));
typedef float f32x4  __attribute__((ext_vector_type(4)));

static constexpr int OFF_RECON  = 0;
static constexpr int OFF_MU     = 1605632;
static constexpr int OFF_LV     = 1736704;
static constexpr int OFF_LOGITS = 1867776;
static constexpr int OFF_PROBS  = 1884160;

// workspace layout (float units)
static constexpr size_t WS_U    = 0;         // 25,690,112 fl
static constexpr size_t WS_PART = 25690112;  // 524,288 fl (fc partials; reused by k_prep)
static constexpr size_t WS_Z    = 26214400;  // 131,072 fl
static constexpr size_t WS_IDX  = 26345472;  // 2,048 ints = 512 fl
static constexpr size_t WS_WENC = 26345984;  // encoder split weights
static constexpr size_t W2S_OFF = 0;         // 110,592 fl
static constexpr size_t W3S_OFF = 110592;    // 442,368 fl
static constexpr size_t HFC_OFF = 0;         // hfcb bf16 [n][49][32] in U
static constexpr size_t D1O_OFF = 3211264;   // d1o bf16 [n][196][64] in U
static constexpr size_t W1B_OFF = 0;         // in part region
static constexpr size_t WCB_OFF = 73728;     // in part region

__device__ __forceinline__ float relu_f(float v) { return v > 0.f ? v : 0.f; }
__device__ __forceinline__ float elu_f(float v)  { return v > 0.f ? v : expm1f(v); }
__device__ __forceinline__ short f2b(float v) {
  __hip_bfloat16 h = __float2bfloat16(v);
  short s; __builtin_memcpy(&s, &h, 2); return s;
}
__device__ __forceinline__ float s2f(short s) {
  unsigned v = ((unsigned)(unsigned short)s) << 16;
  float f; __builtin_memcpy(&f, &v, 4); return f;
}
__device__ __forceinline__ float blo(unsigned u) {
  unsigned v = u << 16; float f; __builtin_memcpy(&f, &v, 4); return f;
}
__device__ __forceinline__ float bhi(unsigned u) {
  unsigned v = u & 0xffff0000u; float f; __builtin_memcpy(&f, &v, 4); return f;
}

// ---------------------------------------------------------------------------
// one-time encoder weight 3-split (h,m,l), slot-duplicated x4 along k.
// ---------------------------------------------------------------------------
__global__ __launch_bounds__(256) void k_prep_enc(
    const float* __restrict__ ew2, const float* __restrict__ ew3,
    unsigned short* __restrict__ w2s, unsigned short* __restrict__ w3s)
{
  const int u = blockIdx.x * 256 + threadIdx.x;
  if (u >= 276480) return;
  float w; uint2* dst; int pass;
  if (u < 55296) {
    int chunk = u / 13824, r = u % 13824;
    pass = r / 4608; int r2 = r % 4608;
    int tap = r2 / 512, r3 = r2 % 512;
    int oc = r3 / 8, ic = r3 % 8;
    w = ew2[oc * 288 + (chunk * 8 + ic) * 9 + tap];
    dst = (uint2*)w2s + u;
  } else {
    int u2 = u - 55296;
    int chunk = u2 / 27648, r = u2 % 27648;
    pass = r / 9216; int r2 = r % 9216;
    int tap = r2 / 1024, r3 = r2 % 1024;
    int oc = r3 / 8, ic = r3 % 8;
    w = ew3[oc * 576 + (chunk * 8 + ic) * 9 + tap];
    dst = (uint2*)w3s + u2;
  }
  short h = f2b(w); float hf = s2f(h);
  short mm = f2b(w - hf); float mf = s2f(mm);
  short ll = f2b(w - hf - mf);
  short val = (pass == 0) ? h : (pass == 1) ? mm : ll;
  unsigned vv = (unsigned)(unsigned short)val | ((unsigned)(unsigned short)val << 16);
  uint2 pk; pk.x = vv; pk.y = vv;
  *dst = pk;
}

// ---------------------------------------------------------------------------
// conv1 (1->32, exact fp32) fused with conv2 (32->64, s2) via 3-split MFMA.
// ---------------------------------------------------------------------------
__global__ __launch_bounds__(256, 2) void k_conv12(
    const float* __restrict__ x,
    const float* __restrict__ w1, const float* __restrict__ b1,
    const float* __restrict__ b2g, const unsigned short* __restrict__ w2s,
    float* __restrict__ h2f)
{
  __shared__ float sX[900];
  __shared__ float sB2[64];
  __shared__ __align__(16) short sH[900 * 40];

  const int n = blockIdx.x, t = threadIdx.x;

  for (int idx = t; idx < 900; idx += 256) {
    int yy = idx / 30, xx = idx % 30;
    float v = 0.f;
    if (yy >= 1 && yy <= 28 && xx >= 1 && xx <= 28)
      v = x[n * 784 + (yy - 1) * 28 + (xx - 1)];
    sX[idx] = v;
  }
  if (t < 64) sB2[t] = b2g[t];
  for (int bi = t; bi < 116; bi += 256) {
    int p;
    if (bi < 30) p = bi;
    else if (bi < 60) p = 870 + (bi - 30);
    else if (bi < 88) p = (bi - 59) * 30;
    else p = (bi - 87) * 30 + 29;
    unsigned* d = (unsigned*)&sH[p * 40];
    #pragma unroll
    for (int j = 0; j < 20; ++j) d[j] = 0u;
  }
  __syncthreads();

  float xw[4][9];
  int hp[4]; bool pvld[4];
  #pragma unroll
  for (int i = 0; i < 4; ++i) {
    int p = t + 256 * i;
    pvld[i] = (p < 784);
    int yy = pvld[i] ? p / 28 : 0, xx = pvld[i] ? p % 28 : 0;
    hp[i] = (yy + 1) * 30 + xx + 1;
    #pragma unroll
    for (int k = 0; k < 9; ++k)
      xw[i][k] = sX[(yy + k / 3) * 30 + xx + (k % 3)];
  }

  const int lane = t & 63, wv = t >> 6;
  const int q = lane >> 4, m16 = lane & 15;
  const int nth = wv & 1, mh = wv >> 1;

  int abase[7];
  #pragma unroll
  for (int mtl = 0; mtl < 7; ++mtl) {
    int m = (mh * 7 + mtl) * 16 + m16; if (m > 195) m = 195;
    int yy = m / 14, xx = m % 14;
    abase[mtl] = (yy * 60 + xx * 2) * 40 + q * 8;
  }
  f32x4 acc[7][2];
  #pragma unroll
  for (int a = 0; a < 7; ++a) { acc[a][0] = (f32x4)0.f; acc[a][1] = (f32x4)0.f; }

  for (int c = 0; c < 4; ++c) {
    #pragma unroll
    for (int o = 0; o < 8; ++o) {
      const int oc = c * 8 + o;
      float wr[9];
      #pragma unroll
      for (int k = 0; k < 9; ++k) wr[k] = w1[oc * 9 + k];
      const float bb = b1[oc];
      #pragma unroll
      for (int i = 0; i < 4; ++i) if (pvld[i]) {
        float v = bb;
        #pragma unroll
        for (int k = 0; k < 9; ++k) v += xw[i][k] * wr[k];
        v = relu_f(v);
        short h = f2b(v); float hf = s2f(h);
        short mm = f2b(v - hf); float mf = s2f(mm);
        short ll = f2b(v - hf - mf);
        uint2 pk;
        pk.x = (unsigned)(unsigned short)h | ((unsigned)(unsigned short)mm << 16);
        pk.y = (unsigned)(unsigned short)ll;
        *(uint2*)&sH[hp[i] * 40 + o * 4] = pk;
      }
    }
    __syncthreads();

    const unsigned short* wb = w2s + (size_t)c * 55296;
    for (int tap = 0; tap < 9; ++tap) {
      const int toff = ((tap / 3) * 30 + (tap % 3)) * 40;
      bf16x8 A[7];
      #pragma unroll
      for (int mtl = 0; mtl < 7; ++mtl)
        A[mtl] = *(const bf16x8*)&sH[abase[mtl] + toff];
      #pragma unroll
      for (int pass = 0; pass < 3; ++pass) {
        #pragma unroll
        for (int ntl = 0; ntl < 2; ++ntl) {
          const int ocl = nth * 32 + ntl * 16 + m16;
          bf16x8 B = *(const bf16x8*)&wb[((pass * 9 + tap) * 64 + ocl) * 32 + q * 8];
          #pragma unroll
          for (int mtl = 0; mtl < 7; ++mtl)
            acc[mtl][ntl] = __builtin_amdgcn_mfma_f32_16x16x32_bf16(A[mtl], B, acc[mtl][ntl], 0, 0, 0);
        }
      }
    }
    __syncthreads();
  }

  #pragma unroll
  for (int mtl = 0; mtl < 7; ++mtl) {
    const int mt = mh * 7 + mtl;
    #pragma unroll
    for (int ntl = 0; ntl < 2; ++ntl) {
      const int oc = nth * 32 + ntl * 16 + m16;
      const float bb = sB2[oc];
      #pragma unroll
      for (int r = 0; r < 4; ++r) {
        int p = mt * 16 + q * 4 + r;
        if (p < 196)
          h2f[(size_t)n * 12544 + p * 64 + oc] = relu_f(acc[mtl][ntl][r] + bb);
      }
    }
  }
}

// ---------------------------------------------------------------------------
// conv3 (64->128, s2) via 3-split MFMA, 4 samples per block.
// ---------------------------------------------------------------------------
__global__ __launch_bounds__(256, 2) void k_conv3(
    float* hb,
    const unsigned short* __restrict__ w3s,
    const float* __restrict__ b3)
{
  __shared__ __align__(16) short sIn[4 * 256 * 40];
  __shared__ float sB3[128];
  const int n0 = blockIdx.x * 4, t = threadIdx.x;
  if (t < 128) sB3[t] = b3[t];
  for (int bi = t; bi < 240; bi += 256) {
    int s = bi / 60, r = bi % 60;
    int p;
    if (r < 16) p = r;
    else if (r < 32) p = 240 + (r - 16);
    else if (r < 46) p = (r - 31) * 16;
    else p = (r - 45) * 16 + 15;
    unsigned* d = (unsigned*)&sIn[(s * 256 + p) * 40];
    #pragma unroll
    for (int j = 0; j < 20; ++j) d[j] = 0u;
  }
  const int lane = t & 63, wv = t >> 6;
  const int q = lane >> 4, m16 = lane & 15;
  const int ntp = wv & 1, mh = wv >> 1;
  int abase[7];
  #pragma unroll
  for (int mtl = 0; mtl < 7; ++mtl) {
    int m = (mh * 7 + mtl) * 16 + m16; if (m > 195) m = 195;
    int s = m / 49, pix = m % 49;
    int yy = pix / 7, xx = pix % 7;
    abase[mtl] = (s * 256 + yy * 32 + xx * 2) * 40 + q * 8;
  }
  f32x4 acc[7][4];
  #pragma unroll
  for (int a = 0; a < 7; ++a)
    #pragma unroll
    for (int b = 0; b < 4; ++b) acc[a][b] = (f32x4)0.f;
  __syncthreads();

  for (int c = 0; c < 8; ++c) {
    __syncthreads();
    for (int u = t; u < 784; u += 256) {
      int s = u / 196, pix = u % 196;
      int rr = pix / 14 + 1, cc = pix % 14 + 1;
      const float* src = &hb[(size_t)(n0 + s) * 12544 + pix * 64 + c * 8];
      float4 v0 = *(const float4*)src;
      float4 v1 = *(const float4*)(src + 4);
      float vv[8] = {v0.x, v0.y, v0.z, v0.w, v1.x, v1.y, v1.z, v1.w};
      short* drow = &sIn[(s * 256 + rr * 16 + cc) * 40];
      #pragma unroll
      for (int ic = 0; ic < 8; ++ic) {
        float v = vv[ic];
        short h = f2b(v); float hf = s2f(h);
        short mm = f2b(v - hf); float mf = s2f(mm);
        short ll = f2b(v - hf - mf);
        uint2 pk;
        pk.x = (unsigned)(unsigned short)h | ((unsigned)(unsigned short)mm << 16);
        pk.y = (unsigned)(unsigned short)ll;
        *(uint2*)&drow[ic * 4] = pk;
      }
    }
    __syncthreads();

    const unsigned short* wc = w3s + (size_t)c * 110592;
    for (int tap = 0; tap < 9; ++tap) {
      const int toff = ((tap / 3) * 16 + (tap % 3)) * 40;
      bf16x8 A[7];
      #pragma unroll
      for (int mtl = 0; mtl < 7; ++mtl)
        A[mtl] = *(const bf16x8*)&sIn[abase[mtl] + toff];
      #pragma unroll
      for (int pass = 0; pass < 3; ++pass) {
        #pragma unroll
        for (int ntl = 0; ntl < 4; ++ntl) {
          const int oc = ntp * 64 + ntl * 16 + m16;
          bf16x8 B = *(const bf16x8*)&wc[((pass * 9 + tap) * 128 + oc) * 32 + q * 8];
          #pragma unroll
          for (int mtl = 0; mtl < 7; ++mtl)
            acc[mtl][ntl] = __builtin_amdgcn_mfma_f32_16x16x32_bf16(A[mtl], B, acc[mtl][ntl], 0, 0, 0);
        }
      }
    }
  }

  #pragma unroll
  for (int mtl = 0; mtl < 7; ++mtl) {
    const int mt = mh * 7 + mtl;
    #pragma unroll
    for (int ntl = 0; ntl < 4; ++ntl) {
      const int oc = ntp * 64 + ntl * 16 + m16;
      const float bb = sB3[oc];
      #pragma unroll
      for (int r = 0; r < 4; ++r) {
        int m = mt * 16 + q * 4 + r;
        if (m < 196) {
          int s = m / 49, pix = m % 49;
          hb[(size_t)(n0 + s) * 12544 + oc * 49 + pix] = relu_f(acc[mtl][ntl][r] + bb);
        }
      }
    }
  }
}

// ---------------------------------------------------------------------------
// fc GEMM: rows at stride 12544 (in-place h3), mu/lv, K-split 2 (fp32)
// ---------------------------------------------------------------------------
__global__ __launch_bounds__(256) void k_fc(
    const float* __restrict__ h3,
    const float* __restrict__ w_mu, const float* __restrict__ w_lv,
    float* __restrict__ part)
{
  __shared__ float As[16 * 65];
  __shared__ float Bs[16 * 64];
  const int bx = blockIdx.x, by = blockIdx.y, bz = blockIdx.z;
  const float* __restrict__ W = by ? w_lv : w_mu;
  const int t = threadIdx.x;
  const int tx = t & 15, ty = t >> 4;
  const int m0 = bx * 64;
  const int k0base = bz * 3136;
  const int ar = t >> 2, ac = (t & 3) * 4;
  const int bk = t >> 4, bn = (t & 15) * 4;
  float acc[4][4];
  #pragma unroll
  for (int i = 0; i < 4; ++i)
    #pragma unroll
    for (int j = 0; j < 4; ++j) acc[i][j] = 0.f;

  for (int kt = 0; kt < 196; ++kt) {
    const int k0 = k0base + kt * 16;
    float4 av = *(const float4*)&h3[(size_t)(m0 + ar) * 12544 + k0 + ac];
    float4 bv = *(const float4*)&W[(size_t)(k0 + bk) * 64 + bn];
    __syncthreads();
    As[(ac + 0) * 65 + ar] = av.x;
    As[(ac + 1) * 65 + ar] = av.y;
    As[(ac + 2) * 65 + ar] = av.z;
    As[(ac + 3) * 65 + ar] = av.w;
    *(float4*)&Bs[bk * 64 + bn] = bv;
    __syncthreads();
    #pragma unroll
    for (int kk = 0; kk < 16; ++kk) {
      float a[4], b[4];
      #pragma unroll
      for (int i = 0; i < 4; ++i) a[i] = As[kk * 65 + ty * 4 + i];
      #pragma unroll
      for (int j = 0; j < 4; ++j) b[j] = Bs[kk * 64 + tx * 4 + j];
      #pragma unroll
      for (int i = 0; i < 4; ++i)
        #pragma unroll
        for (int j = 0; j < 4; ++j) acc[i][j] += a[i] * b[j];
    }
  }
  const int slab = by * 2 + bz;
  #pragma unroll
  for (int i = 0; i < 4; ++i)
    #pragma unroll
    for (int j = 0; j < 4; ++j)
      part[(size_t)slab * 131072 + (size_t)(m0 + ty * 4 + i) * 64 + tx * 4 + j] = acc[i][j];
}

// ---------------------------------------------------------------------------
// gate (strict fp32)
// ---------------------------------------------------------------------------
__global__ __launch_bounds__(64) void k_gate(
    const float* __restrict__ part,
    const float* __restrict__ b_mu, const float* __restrict__ b_lv,
    const float* __restrict__ eps,
    const float* __restrict__ gw1, const float* __restrict__ gb1,
    const float* __restrict__ gw2, const float* __restrict__ gb2,
    const float* __restrict__ gw3, const float* __restrict__ gb3,
    float* __restrict__ out, float* __restrict__ zbuf, int* __restrict__ idxbuf)
{
  __shared__ float sZ[64][65];
  __shared__ float sG1[64][65];
  __shared__ float sG2[64][33];
  const int t = threadIdx.x;
  const int m = blockIdx.x * 64 + t;

  for (int k = 0; k < 64; ++k) {
    float mu = b_mu[k] + part[(size_t)m * 64 + k] + part[131072 + (size_t)m * 64 + k];
    float lv = b_lv[k] + part[262144 + (size_t)m * 64 + k] + part[393216 + (size_t)m * 64 + k];
    out[OFF_MU + m * 64 + k] = mu;
    out[OFF_LV + m * 64 + k] = lv;
    float zz = mu + eps[m * 64 + k] * expf(0.5f * lv);
    sZ[t][k] = zz;
    zbuf[m * 64 + k] = zz;
  }
  for (int j = 0; j < 64; ++j) {
    float a = gb1[j];
    for (int k = 0; k < 64; ++k) a += sZ[t][k] * gw1[k * 64 + j];
    sG1[t][j] = relu_f(a);
  }
  for (int j = 0; j < 32; ++j) {
    float a = gb2[j];
    for (int k = 0; k < 64; ++k) a += sG1[t][k] * gw2[k * 32 + j];
    sG2[t][j] = relu_f(a);
  }
  float l[8];
  #pragma unroll
  for (int j = 0; j < 8; ++j) {
    float a = gb3[j];
    for (int k = 0; k < 32; ++k) a += sG2[t][k] * gw3[k * 8 + j];
    l[j] = a;
  }
  float mx = l[0];
  #pragma unroll
  for (int j = 1; j < 8; ++j) mx = fmaxf(mx, l[j]);
  float p[8]; float s = 0.f;
  #pragma unroll
  for (int j = 0; j < 8; ++j) { p[j] = expf(l[j] - mx); s += p[j]; }
  const float inv = 1.f / s;
  float best = -1.f; int bi = 0;
  #pragma unroll
  for (int j = 0; j < 8; ++j) {
    float pj = p[j] * inv;
    out[OFF_PROBS + m * 8 + j] = pj;
    out[OFF_LOGITS + m * 8 + j] = logf(pj + 1e-8f);
    if (pj > best) { best = pj; bi = j; }
  }
  idxbuf[m] = bi;
}

// ---------------------------------------------------------------------------
// one-time decoder weight repack to bf16 (into dead part region).
// ---------------------------------------------------------------------------
__global__ __launch_bounds__(256) void k_prep(
    const float* __restrict__ dw1, const float* __restrict__ dw2,
    unsigned short* __restrict__ w1b, unsigned short* __restrict__ wcb)
{
  const int e = blockIdx.x, job = blockIdx.y, t = threadIdx.x;
  if (job == 0) {
    for (int idx = t; idx < 18432; idx += 256) {
      int tap = idx >> 11, oc = (idx >> 5) & 63, ic = idx & 31;
      w1b[(size_t)e * 18432 + idx] =
          (unsigned short)f2b(dw1[(size_t)e * 18432 + (oc * 32 + ic) * 9 + tap]);
    }
  } else {
    const int par = job - 1, py = par >> 1, px = par & 1;
    for (int v = t; v < 8192; v += 256) {
      int s = v >> 10, oc = (v >> 5) & 31, ic = v & 31;
      int tap = s >> 1, h = s & 1;
      int ty = tap >> 1, tx = tap & 1;
      int icg = h * 32 + ic;
      int ys = (ty == 0) ? 0 : (1 + py);
      int yc = (ty == py) ? 1 : 2;
      int xs = (tx == 0) ? 0 : (1 + px);
      int xc = (tx == px) ? 1 : 2;
      const float* wp = &dw2[(size_t)e * 18432 + (oc * 64 + icg) * 9];
      float a = 0.f;
      for (int ky = ys; ky < ys + yc; ++ky)
        for (int kx = xs; kx < xs + xc; ++kx)
          a += wp[ky * 3 + kx];
      wcb[((size_t)e * 4 + par) * 8192 + v] = (unsigned short)f2b(a);
    }
  }
}

// ---------------------------------------------------------------------------
// decoder fc: z[64] @ d_fc_w[e][64][1568] + b -> hfcb bf16 [n][pix49][ic32]
// float4 weight stream (bit-identical accumulation order).
// ---------------------------------------------------------------------------
__global__ __launch_bounds__(256) void k_dfc(
    const float* __restrict__ zbuf, const int* __restrict__ idxbuf,
    const float* __restrict__ fcw, const float* __restrict__ fcb,
    unsigned* __restrict__ hfcb)
{
  __shared__ float sZ[64];
  __shared__ __align__(16) unsigned short sO[1568];
  const int n = blockIdx.x, t = threadIdx.x;
  const int e = idxbuf[n];
  if (t < 64) sZ[t] = zbuf[n * 64 + t];
  __syncthreads();
  const float* __restrict__ W = fcw + (size_t)e * 100352;
  const int i40 = t, i41 = t + 256;
  const bool v1 = (i41 < 392);
  float a0[4], a1[4];
  {
    float4 b0 = *(const float4*)&fcb[e * 1568 + i40 * 4];
    a0[0] = b0.x; a0[1] = b0.y; a0[2] = b0.z; a0[3] = b0.w;
    if (v1) {
      float4 b1v = *(const float4*)&fcb[e * 1568 + i41 * 4];
      a1[0] = b1v.x; a1[1] = b1v.y; a1[2] = b1v.z; a1[3] = b1v.w;
    } else { a1[0] = a1[1] = a1[2] = a1[3] = 0.f; }
  }
  for (int k = 0; k < 64; ++k) {
    const float zk = sZ[k];
    float4 w0 = *(const float4*)&W[k * 1568 + i40 * 4];
    a0[0] += zk * w0.x; a0[1] += zk * w0.y; a0[2] += zk * w0.z; a0[3] += zk * w0.w;
    if (v1) {
      float4 w1v = *(const float4*)&W[k * 1568 + i41 * 4];
      a1[0] += zk * w1v.x; a1[1] += zk * w1v.y; a1[2] += zk * w1v.z; a1[3] += zk * w1v.w;
    }
  }
  #pragma unroll
  for (int c = 0; c < 4; ++c) {
    int j = i40 * 4 + c;
    int ic = j / 49, p = j % 49;
    sO[p * 32 + ic] = (unsigned short)f2b(a0[c]);
  }
  if (v1) {
    #pragma unroll
    for (int c = 0; c < 4; ++c) {
      int j = i41 * 4 + c;
      int ic = j / 49, p = j % 49;
      sO[p * 32 + ic] = (unsigned short)f2b(a1[c]);
    }
  }
  __syncthreads();
  for (int idx = t; idx < 784; idx += 256)
    hfcb[(size_t)n * 784 + idx] = ((const unsigned*)sO)[idx];
}

// ---------------------------------------------------------------------------
// decoder conv1 via bf16 MFMA implicit GEMM. Output d1o[n][196][64] bf16.
// ---------------------------------------------------------------------------
__global__ __launch_bounds__(256) void k_d1(
    const unsigned* __restrict__ hfcb, const int* __restrict__ idxbuf,
    const unsigned* __restrict__ w1b, const float* __restrict__ b,
    __hip_bfloat16* __restrict__ d1o)
{
  __shared__ __align__(16) short sIn[256 * 40];
  __shared__ __align__(16) short sW[9 * 64 * 32];
  __shared__ float sB[64];

  const int n = blockIdx.x, t = threadIdx.x;
  const int e = idxbuf[n];

  {
    int r = t >> 4, c = t & 15;
    bool inter = (r >= 1 && r <= 14 && c >= 1 && c <= 14);
    int src = inter ? (((r - 1) >> 1) * 7 + ((c - 1) >> 1)) : 0;
    const unsigned* hp = &hfcb[(size_t)n * 784 + src * 16];
    unsigned* dst = (unsigned*)&sIn[t * 40];
    #pragma unroll
    for (int i = 0; i < 16; ++i) dst[i] = inter ? hp[i] : 0u;
  }
  {
    const unsigned* wsrc = w1b + (size_t)e * 9216;
    unsigned* wd = (unsigned*)sW;
    for (int idx = t; idx < 9216; idx += 256) wd[idx] = wsrc[idx];
  }
  if (t < 64) sB[t] = b[e * 64 + t];
  __syncthreads();

  const int wv = t >> 6, lane = t & 63;
  const int q = lane >> 4, m16 = lane & 15;
  const int ocl = wv * 16 + m16;

  f32x4 acc[13];
  int abase[13];
  #pragma unroll
  for (int mt = 0; mt < 13; ++mt) {
    acc[mt] = (f32x4)0.f;
    int p = mt * 16 + m16; if (p > 195) p = 195;
    int y = p / 14, x = p % 14;
    abase[mt] = (y * 16 + x) * 40 + q * 8;
  }

  for (int tap = 0; tap < 9; ++tap) {
    const int ky = tap / 3, kx = tap % 3;
    const int toff = (ky * 16 + kx) * 40;
    bf16x8 bfrag = *(const bf16x8*)&sW[tap * 2048 + ocl * 32 + q * 8];
    #pragma unroll
    for (int mt = 0; mt < 13; ++mt) {
      bf16x8 afrag = *(const bf16x8*)&sIn[abase[mt] + toff];
      acc[mt] = __builtin_amdgcn_mfma_f32_16x16x32_bf16(afrag, bfrag, acc[mt], 0, 0, 0);
    }
  }

  const float bias = sB[ocl];
  #pragma unroll
  for (int mt = 0; mt < 13; ++mt) {
    #pragma unroll
    for (int r = 0; r < 4; ++r) {
      int p = mt * 16 + q * 4 + r;
      if (p < 196) {
        float v = elu_f(acc[mt][r] + bias);
        short s = f2b(v);
        __builtin_memcpy(&d1o[(size_t)n * 12544 + p * 64 + ocl], &s, 2);
      }
    }
  }
}

// ---------------------------------------------------------------------------
// fused decoder conv2+conv3, BOTH on MFMA.
// Per parity (py,px):
//   d2: C[196x32] = P[196x(4tap*64ic)] * Wc  (Wc precomputed bf16, in sU)
//   epilogue: bias+elu -> d2buf in sU [p196][40] bf16
//   d3: C_par[196x16] = d2buf[196x32] * B3  (B3[ic32][tap16], cols 0-8 = w3)
//       -> sC[p196][9] fp32
//   gather: per output pixel, add sC entries for taps whose input parity
//           matches (py,px)  (<=4 per parity, 9 total across parities)
// LDS: sD1 36,864 + sU 16,384 + sC 7,056 + sW3b 1,024 + sB2 128 = 61,456 B.
// ---------------------------------------------------------------------------
__global__ __launch_bounds__(256) void k_d23(
    const unsigned* __restrict__ d1u,
    const int* __restrict__ idxbuf,
    const unsigned* __restrict__ wcb,
    const float* __restrict__ b2,
    const float* __restrict__ w3, const float* __restrict__ b3,
    float* __restrict__ out)
{
  __shared__ __align__(16) short sD1[256 * 72];
  __shared__ __align__(16) short sU[8192];
  __shared__ __align__(16) short sW3b[512];   // [n16][k32] for d3 B-frag
  __shared__ float sC[196 * 9];
  __shared__ float sB2[32];

  const int n = blockIdx.x, t = threadIdx.x;
  const int e = idxbuf[n];

  {
    unsigned* d = (unsigned*)sD1;
    for (int idx = t; idx < 9216; idx += 256) d[idx] = 0u;
  }
  __syncthreads();
  {
    unsigned* d = (unsigned*)sD1;
    for (int idx = t; idx < 6272; idx += 256) {
      unsigned v = d1u[(size_t)n * 6272 + idx];
      int p = idx >> 5, icp = idx & 31;
      int r = p / 14, c = p % 14;
      d[((r + 1) * 16 + (c + 1)) * 36 + icp] = v;
    }
  }
  for (int j = t; j < 512; j += 256) {
    int nn = j >> 5, k = j & 31;
    sW3b[nn * 32 + k] = (nn < 9) ? f2b(w3[e * 288 + k * 9 + nn]) : (short)0;
  }
  if (t < 32) sB2[t] = b2[e * 32 + t];
  __syncthreads();

  const int wv = t >> 6, lane = t & 63;
  const int q = lane >> 4, m16 = lane & 15;
  const int nt = wv & 1, mh = wv >> 1;
  const int ocl = nt * 16 + m16;
  const int nm = (mh == 0) ? 7 : 6;

  // d3 B-fragment: constant across parities
  const bf16x8 b3f = *(const bf16x8*)&sW3b[m16 * 32 + q * 8];

  // d3 m-tiles for this wave: mt = wv + 4*i
  int mt3[4], ab3[4];
  const int nmt3 = (wv == 0) ? 4 : 3;
  #pragma unroll
  for (int i = 0; i < 4; ++i) {
    int mt = wv + 4 * i; if (mt > 12) mt = 12;
    mt3[i] = mt;
    int p = mt * 16 + m16; if (p > 195) p = 195;
    ab3[i] = p * 40 + q * 8;
  }

  int PY[4], PX[4];
  #pragma unroll
  for (int g = 0; g < 4; ++g) {
    int P = t + 256 * g;
    PY[g] = (P < 784) ? P / 28 : -100;
    PX[g] = (P < 784) ? P % 28 : 0;
  }
  float racc[4] = {0.f, 0.f, 0.f, 0.f};

  int ab0[7];
  #pragma unroll
  for (int im = 0; im < 7; ++im) {
    int mt = mh + 2 * im;
    int p = mt * 16 + m16; if (p > 195) p = 195;
    int a = p / 14, bb = p % 14;
    ab0[im] = (a * 16 + bb) * 72 + q * 8;
  }

  for (int par = 0; par < 4; ++par) {
    const int py = par >> 1, px = par & 1;

    // ---- load Wc (coalesced) ----
    {
      const unsigned* wc = wcb + ((size_t)e * 4 + par) * 4096;
      unsigned* du = (unsigned*)sU;
      for (int v = t; v < 4096; v += 256) du[v] = wc[v];
    }
    __syncthreads();

    // ---- d2 MFMA ----
    f32x4 acc[7];
    #pragma unroll
    for (int im = 0; im < 7; ++im) acc[im] = (f32x4)0.f;
    const int pbase = (py * 16 + px) * 72;
    for (int s = 0; s < 8; ++s) {
      int tap = s >> 1, h = s & 1;
      int ty = tap >> 1, tx = tap & 1;
      int toff = pbase + (ty * 16 + tx) * 72 + h * 32;
      bf16x8 bfrag = *(const bf16x8*)&sU[s * 1024 + ocl * 32 + q * 8];
      for (int im = 0; im < nm; ++im) {
        bf16x8 afrag = *(const bf16x8*)&sD1[ab0[im] + toff];
        acc[im] = __builtin_amdgcn_mfma_f32_16x16x32_bf16(afrag, bfrag, acc[im], 0, 0, 0);
      }
    }
    __syncthreads();   // Wc consumed before d2buf overwrites sU

    // ---- epilogue: bias + elu -> d2buf [p196][40] bf16 ----
    {
      const float bias = sB2[ocl];
      for (int im = 0; im < nm; ++im) {
        int mt = mh + 2 * im;
        #pragma unroll
        for (int r = 0; r < 4; ++r) {
          int p = mt * 16 + q * 4 + r;
          if (p < 196) sU[p * 40 + ocl] = f2b(elu_f(acc[im][r] + bias));
        }
      }
    }
    __syncthreads();

    // ---- d3 MFMA: C_par = d2buf * B3 -> sC fp32 [196][9] ----
    for (int i = 0; i < nmt3; ++i) {
      bf16x8 af = *(const bf16x8*)&sU[ab3[i]];
      f32x4 a3 = (f32x4)0.f;
      a3 = __builtin_amdgcn_mfma_f32_16x16x32_bf16(af, b3f, a3, 0, 0, 0);
      if (m16 < 9) {
        #pragma unroll
        for (int r = 0; r < 4; ++r) {
          int p = mt3[i] * 16 + q * 4 + r;
          if (p < 196) sC[p * 9 + m16] = a3[r];
        }
      }
    }
    __syncthreads();

    // ---- gather: taps of this parity ----
    #pragma unroll
    for (int g = 0; g < 4; ++g) {
      const int Y = PY[g], X = PX[g];
      if (Y < 0) continue;
      int RS[2]; int nr = 0;
      if ((Y & 1) == py) { RS[0] = Y; nr = 1; }
      else { if (Y > 0) RS[nr++] = Y - 1; if (Y < 27) RS[nr++] = Y + 1; }
      int CS[2]; int nc = 0;
      if ((X & 1) == px) { CS[0] = X; nc = 1; }
      else { if (X > 0) CS[nc++] = X - 1; if (X < 27) CS[nc++] = X + 1; }
      float s = 0.f;
      for (int ir = 0; ir < nr; ++ir) {
        const int R = RS[ir];
        const int a = (R - py) >> 1, ky = R - Y + 1;
        for (int jc = 0; jc < nc; ++jc) {
          const int C = CS[jc];
          const int bq = (C - px) >> 1, kx = C - X + 1;
          s += sC[(a * 14 + bq) * 9 + ky * 3 + kx];
        }
      }
      racc[g] += s;
    }
    __syncthreads();   // sC consumed before next parity's d3 writes
  }

  const float b3e = b3[e];
  #pragma unroll
  for (int g = 0; g < 4; ++g) {
    int P = t + 256 * g;
    if (P < 784)
      out[OFF_RECON + (size_t)n * 784 + P] = 1.f / (1.f + expf(-(racc[g] + b3e)));
  }
}

// ---------------------------------------------------------------------------
extern "C" void kernel_launch(void* const* d_in, const int* in_sizes, int n_in,
                              void* d_out, int out_size, void* d_ws, size_t ws_size,
                              hipStream_t stream) {
  const float* x    = (const float*)d_in[0];
  const float* eps  = (const float*)d_in[1];
  const float* ew1  = (const float*)d_in[2];
  const float* eb1  = (const float*)d_in[3];
  const float* ew2  = (const float*)d_in[4];
  const float* eb2  = (const float*)d_in[5];
  const float* ew3  = (const float*)d_in[6];
  const float* eb3  = (const float*)d_in[7];
  const float* wmu  = (const float*)d_in[8];
  const float* bmu  = (const float*)d_in[9];
  const float* wlv  = (const float*)d_in[10];
  const float* blv  = (const float*)d_in[11];
  const float* gw1  = (const float*)d_in[12];
  const float* gb1  = (const float*)d_in[13];
  const float* gw2  = (const float*)d_in[14];
  const float* gb2  = (const float*)d_in[15];
  const float* gw3  = (const float*)d_in[16];
  const float* gb3  = (const float*)d_in[17];
  const float* dfcw = (const float*)d_in[18];
  const float* dfcb = (const float*)d_in[19];
  const float* dw1  = (const float*)d_in[20];
  const float* db1  = (const float*)d_in[21];
  const float* dw2  = (const float*)d_in[22];
  const float* db2  = (const float*)d_in[23];
  const float* dw3  = (const float*)d_in[24];
  const float* db3  = (const float*)d_in[25];

  float* out = (float*)d_out;
  float* ws  = (float*)d_ws;

  float* U    = ws + WS_U;
  float* part = ws + WS_PART;
  float* zb   = ws + WS_Z;
  int*   idx  = (int*)(ws + WS_IDX);
  unsigned* hfcb = (unsigned*)(U + HFC_OFF);
  __hip_bfloat16* d1o = (__hip_bfloat16*)(U + D1O_OFF);
  unsigned short* w1b = (unsigned short*)(part + W1B_OFF);
  unsigned short* wcb = (unsigned short*)(part + WCB_OFF);
  unsigned short* w2s = (unsigned short*)(ws + WS_WENC + W2S_OFF);
  unsigned short* w3s = (unsigned short*)(ws + WS_WENC + W3S_OFF);

  k_prep_enc<<<1080, 256, 0, stream>>>(ew2, ew3, w2s, w3s);
  k_conv12<<<NB, 256, 0, stream>>>(x, ew1, eb1, eb2, w2s, U);
  k_conv3 <<<512, 256, 0, stream>>>(U, w3s, eb3);
  k_fc    <<<dim3(32, 2, 2), 256, 0, stream>>>(U, wmu, wlv, part);
  k_gate  <<<32, 64, 0, stream>>>(part, bmu, blv, eps, gw1, gb1, gw2, gb2, gw3, gb3,
                                  out, zb, idx);
  k_prep  <<<dim3(8, 5), 256, 0, stream>>>(dw1, dw2, w1b, wcb);
  k_dfc   <<<NB, 256, 0, stream>>>(zb, idx, dfcw, dfcb, hfcb);
  k_d1    <<<NB, 256, 0, stream>>>(hfcb, idx, (const unsigned*)w1b, db1, d1o);
  k_d23   <<<NB, 256, 0, stream>>>((const unsigned*)d1o, idx, (const unsigned*)wcb,
                                   db2, dw3, db3, out);
}